// Round 1
// baseline (496.794 us; speedup 1.0000x reference)
//
#include <hip/hip_runtime.h>

typedef unsigned short ushort_t;
typedef __bf16 bf16x8 __attribute__((ext_vector_type(8)));
typedef float f32x4 __attribute__((ext_vector_type(4)));
typedef unsigned int u32x4 __attribute__((ext_vector_type(4)));
typedef unsigned short us4 __attribute__((ext_vector_type(4)));
typedef unsigned short us8 __attribute__((ext_vector_type(8)));

#define DEVINL __device__ __forceinline__

DEVINL ushort_t f2bf(float f) {
    unsigned u = __float_as_uint(f);
    u += 0x7FFF + ((u >> 16) & 1);   // RNE
    return (ushort_t)(u >> 16);
}
DEVINL float bf2f(ushort_t h) { return __uint_as_float(((unsigned)h) << 16); }

DEVINL void gload_lds16(const void* g, void* l) {
    __builtin_amdgcn_global_load_lds(
        (const __attribute__((address_space(1))) void*)g,
        (__attribute__((address_space(3))) void*)l, 16, 0, 0);
}

DEVINL bf16x8 ld_frag(const ushort_t* p) {
    us8 v = *(const us8*)p;
    return __builtin_bit_cast(bf16x8, v);
}

// ---------------------------------------------------------------- convert
__global__ __launch_bounds__(256) void convert_bf16(const f32x4* __restrict__ in,
                                                    us4* __restrict__ out, int n4) {
    int i = blockIdx.x * 256 + threadIdx.x;
    if (i >= n4) return;
    f32x4 f = in[i];
    us4 o;
    o[0] = f2bf(f[0]); o[1] = f2bf(f[1]); o[2] = f2bf(f[2]); o[3] = f2bf(f[3]);
    out[i] = o;
}

// ---------------------------------------------------------------- GEMM C = A @ W^T
// A[M][K] bf16 row-major, W[N][K] bf16 row-major, C[M][N] (bf16 or f32).
// 128x128 tile, BK=32, 4 waves in 2x2, each wave 64x64 (4x4 of 16x16 MFMA).
template <typename OutT>
__global__ __launch_bounds__(256) void gemm_bt(const ushort_t* __restrict__ A,
                                               const ushort_t* __restrict__ W,
                                               OutT* __restrict__ C,
                                               int M, int N, int K) {
    __shared__ ushort_t As[128 * 32];
    __shared__ ushort_t Bs[128 * 32];
    const int t = threadIdx.x;
    const int w = t >> 6, lane = t & 63;
    const int quad = lane >> 4, l16 = lane & 15;
    const int bm = blockIdx.x * 128, bn = blockIdx.y * 128;
    const int wr = (w >> 1) * 64, wc = (w & 1) * 64;

    f32x4 acc[4][4];
#pragma unroll
    for (int i = 0; i < 4; i++)
#pragma unroll
        for (int j = 0; j < 4; j++) acc[i][j] = f32x4{0.f, 0.f, 0.f, 0.f};

    for (int k0 = 0; k0 < K; k0 += 32) {
        __syncthreads();
#pragma unroll
        for (int i = 0; i < 2; i++) {
            int u = i * 256 + t;          // 16B-chunk index; LDS dest = u*16 (lane-contiguous)
            int row = u >> 2;
            int ce = (u & 3) * 8;         // element offset within 32-elem row
            gload_lds16(A + (size_t)(bm + row) * K + k0 + ce, (char*)As + u * 16);
            gload_lds16(W + (size_t)(bn + row) * K + k0 + ce, (char*)Bs + u * 16);
        }
        __syncthreads();
        bf16x8 af[4], bf[4];
#pragma unroll
        for (int mt = 0; mt < 4; mt++)
            af[mt] = ld_frag(&As[(wr + mt * 16 + l16) * 32 + quad * 8]);
#pragma unroll
        for (int nt = 0; nt < 4; nt++)
            bf[nt] = ld_frag(&Bs[(wc + nt * 16 + l16) * 32 + quad * 8]);
#pragma unroll
        for (int mt = 0; mt < 4; mt++)
#pragma unroll
            for (int nt = 0; nt < 4; nt++)
                acc[mt][nt] = __builtin_amdgcn_mfma_f32_16x16x32_bf16(af[mt], bf[nt],
                                                                      acc[mt][nt], 0, 0, 0);
    }

#pragma unroll
    for (int mt = 0; mt < 4; mt++)
#pragma unroll
        for (int nt = 0; nt < 4; nt++) {
            int row = bm + wr + mt * 16 + quad * 4;
            int col = bn + wc + nt * 16 + l16;
#pragma unroll
            for (int r = 0; r < 4; r++) {
                float v = acc[mt][nt][r];
                if constexpr (sizeof(OutT) == 2)
                    C[(size_t)(row + r) * N + col] = (OutT)f2bf(v);
                else
                    C[(size_t)(row + r) * N + col] = v;
            }
        }
}

// ---------------------------------------------------------------- RoPE + l2norm
// qkv[b*S+s][4096]: cols 0..2047 q (h=n/128), 2048..3071 k (kvh=(n-2048)/128).
// One wave per (b,s,head). Reference uses sin_e=-sin:
//   d<64 : y1 = x1*cos + x2*sin ;  d>=64: y2 = x2*cos - x1*sin
__global__ __launch_bounds__(256) void rope_norm(const ushort_t* __restrict__ qkv,
                                                 const float* __restrict__ cosb,
                                                 const float* __restrict__ sinb,
                                                 ushort_t* __restrict__ q,
                                                 ushort_t* __restrict__ k) {
    int row = blockIdx.x;                 // b*2048 + s
    int b = row >> 11, s = row & 2047;
    int w = threadIdx.x >> 6, lane = threadIdx.x & 63;
    int hh = blockIdx.y * 4 + w;          // 0..23
    const ushort_t* src = qkv + (size_t)row * 4096 + hh * 128;
    float x1 = bf2f(src[lane]);
    float x2 = bf2f(src[lane + 64]);
    float c = cosb[(size_t)row * 128 + lane];
    float sn = sinb[(size_t)row * 128 + lane];
    float y1 = x1 * c + x2 * sn;
    float y2 = x2 * c - x1 * sn;
    float ss = y1 * y1 + y2 * y2;
#pragma unroll
    for (int off = 1; off < 64; off <<= 1) ss += __shfl_xor(ss, off);
    float rinv = rsqrtf(ss * (1.0f / 128.0f) + 1e-6f);
    y1 *= rinv; y2 *= rinv;
    ushort_t* dst;
    if (hh < 16) dst = q + (((size_t)(b * 16 + hh)) * 2048 + s) * 128;
    else         dst = k + (((size_t)(b * 8 + hh - 16)) * 2048 + s) * 128;
    dst[lane] = f2bf(y1);
    dst[lane + 64] = f2bf(y2);
}

// ---------------------------------------------------------------- V transpose
// qkv v-section [b][s][kvh*128+d] -> vt[(b*8+kvh)*128 + d][s]
__global__ __launch_bounds__(256) void v_transpose(const ushort_t* __restrict__ qkv,
                                                   ushort_t* __restrict__ vt) {
    __shared__ ushort_t tile[64 * 72];
    int t = threadIdx.x;
    int s0 = blockIdx.x * 64, d0 = blockIdx.y * 64, bh = blockIdx.z;
    int b = bh >> 3, kvh = bh & 7;
    {
        int sl = t >> 2, c = t & 3;
        const ushort_t* src = qkv + (size_t)(b * 2048 + s0 + sl) * 4096 + 3072 + kvh * 128 + d0 + c * 16;
        u32x4 v0 = *(const u32x4*)src;
        u32x4 v1 = *(const u32x4*)(src + 8);
        *(u32x4*)&tile[sl * 72 + c * 16] = v0;
        *(u32x4*)&tile[sl * 72 + c * 16 + 8] = v1;
    }
    __syncthreads();
    {
        int dl = t >> 2, c = t & 3;
        alignas(16) ushort_t tmp[16];
#pragma unroll
        for (int i = 0; i < 16; i++) tmp[i] = tile[(c * 16 + i) * 72 + dl];
        ushort_t* dst = vt + (size_t)(bh * 128 + d0 + dl) * 2048 + s0 + c * 16;
        *(u32x4*)dst = *(const u32x4*)&tmp[0];
        *(u32x4*)(dst + 8) = *(const u32x4*)&tmp[8];
    }
}

// ---------------------------------------------------------------- Flash attention
// Grid (S/64, NQ, B). 4 waves/block; wave w owns q-rows q0+16w..+15. TK=64.
// Ks [qd][64][32] (k-blocked), Vts [ks][128][32] (k-blocked), Ps per-wave [16][72].
__global__ __launch_bounds__(256) void flash_attn(const ushort_t* __restrict__ q,
                                                  const ushort_t* __restrict__ k,
                                                  const ushort_t* __restrict__ vt,
                                                  ushort_t* __restrict__ attn) {
    __shared__ ushort_t Ks[4 * 64 * 32];
    __shared__ ushort_t Vts[2 * 128 * 32];
    __shared__ ushort_t Ps[4 * 16 * 72];
    const int t = threadIdx.x;
    const int w = t >> 6, lane = t & 63;
    const int quad = lane >> 4, l16 = lane & 15;
    const int q0 = blockIdx.x * 64;
    const int h = blockIdx.y, b = blockIdx.z;
    const int kvh = h >> 1;
    const size_t qbase = ((size_t)(b * 16 + h) * 2048 + q0 + w * 16 + l16) * 128;
    const size_t kbase = ((size_t)(b * 8 + kvh)) * 2048 * 128;
    const size_t vbase = ((size_t)(b * 8 + kvh)) * 128 * 2048;

    bf16x8 qf[4];
#pragma unroll
    for (int qd = 0; qd < 4; qd++) {
        us8 v = *(const us8*)(q + qbase + qd * 32 + quad * 8);
        qf[qd] = __builtin_bit_cast(bf16x8, v);
    }

    f32x4 o[8];
#pragma unroll
    for (int i = 0; i < 8; i++) o[i] = f32x4{0.f, 0.f, 0.f, 0.f};
    float m_r[4], l_r[4];
#pragma unroll
    for (int r = 0; r < 4; r++) { m_r[r] = -3.0e38f; l_r[r] = 0.f; }

    const float scale = 0.08838834764831845f;   // 1/sqrt(128)
    const int ntiles = blockIdx.x + 1;          // causal: kv tiles up to diagonal block
    for (int jt = 0; jt < ntiles; ++jt) {
        const int j0 = jt * 64;
        __syncthreads();
#pragma unroll
        for (int i = 0; i < 4; i++) {           // stage K tile (16KB), k-blocked
            int u = i * 256 + t;
            int qd = u >> 8, rr = (u >> 2) & 63, c4 = u & 3;
            gload_lds16(k + kbase + (size_t)(j0 + rr) * 128 + qd * 32 + c4 * 8,
                        (char*)Ks + u * 16);
        }
#pragma unroll
        for (int i = 0; i < 4; i++) {           // stage Vt tile (16KB), k-blocked
            int u = i * 256 + t;
            int ks = u >> 9, dd = (u >> 2) & 127, c4 = u & 3;
            gload_lds16(vt + vbase + (size_t)dd * 2048 + j0 + ks * 32 + c4 * 8,
                        (char*)Vts + u * 16);
        }
        __syncthreads();

        // S = Q K^T (per wave: 16 x 64)
        f32x4 sc[4];
#pragma unroll
        for (int c = 0; c < 4; c++) {
            sc[c] = f32x4{0.f, 0.f, 0.f, 0.f};
#pragma unroll
            for (int qd = 0; qd < 4; qd++) {
                bf16x8 kf = ld_frag(&Ks[qd * 2048 + (c * 16 + l16) * 32 + quad * 8]);
                sc[c] = __builtin_amdgcn_mfma_f32_16x16x32_bf16(qf[qd], kf, sc[c], 0, 0, 0);
            }
        }
        // scale + causal mask + row max
        float p[4][4], mp[4];
#pragma unroll
        for (int r = 0; r < 4; r++) mp[r] = -3.0e38f;
#pragma unroll
        for (int c = 0; c < 4; c++)
#pragma unroll
            for (int r = 0; r < 4; r++) {
                int qg = q0 + w * 16 + quad * 4 + r;
                int kg = j0 + c * 16 + l16;
                float v = sc[c][r] * scale;
                v = (kg > qg) ? -3.0e38f : v;
                p[c][r] = v;
                mp[r] = fmaxf(mp[r], v);
            }
#pragma unroll
        for (int r = 0; r < 4; r++)
#pragma unroll
            for (int off = 1; off < 16; off <<= 1)
                mp[r] = fmaxf(mp[r], __shfl_xor(mp[r], off));

        float alpha[4], ls[4];
#pragma unroll
        for (int r = 0; r < 4; r++) {
            float mn = fmaxf(m_r[r], mp[r]);
            alpha[r] = __expf(m_r[r] - mn);
            m_r[r] = mn;
            ls[r] = 0.f;
#pragma unroll
            for (int c = 0; c < 4; c++) {
                float e = __expf(p[c][r] - mn);
                p[c][r] = e;
                ls[r] += e;
            }
        }
#pragma unroll
        for (int r = 0; r < 4; r++) {
#pragma unroll
            for (int off = 1; off < 16; off <<= 1) ls[r] += __shfl_xor(ls[r], off);
            l_r[r] = l_r[r] * alpha[r] + ls[r];
        }
#pragma unroll
        for (int od = 0; od < 8; od++)
#pragma unroll
            for (int r = 0; r < 4; r++) o[od][r] *= alpha[r];

        // P: C-layout -> A-layout via per-wave LDS scratch (padded rows, 144B stride)
#pragma unroll
        for (int c = 0; c < 4; c++)
#pragma unroll
            for (int r = 0; r < 4; r++)
                Ps[w * 1152 + (quad * 4 + r) * 72 + c * 16 + l16] = f2bf(p[c][r]);

        // O += P V
#pragma unroll
        for (int ks = 0; ks < 2; ks++) {
            bf16x8 pf = ld_frag(&Ps[w * 1152 + l16 * 72 + ks * 32 + quad * 8]);
#pragma unroll
            for (int od = 0; od < 8; od++) {
                bf16x8 vf = ld_frag(&Vts[ks * 4096 + (od * 16 + l16) * 32 + quad * 8]);
                o[od] = __builtin_amdgcn_mfma_f32_16x16x32_bf16(pf, vf, o[od], 0, 0, 0);
            }
        }
    }

    float rl[4];
#pragma unroll
    for (int r = 0; r < 4; r++) rl[r] = 1.0f / l_r[r];
    const size_t obase = ((size_t)(b * 2048 + q0 + w * 16 + quad * 4)) * 2048 + h * 128;
#pragma unroll
    for (int od = 0; od < 8; od++)
#pragma unroll
        for (int r = 0; r < 4; r++)
            attn[obase + (size_t)r * 2048 + od * 16 + l16] = f2bf(o[od][r] * rl[r]);
}

// ---------------------------------------------------------------- launch
extern "C" void kernel_launch(void* const* d_in, const int* in_sizes, int n_in,
                              void* d_out, int out_size, void* d_ws, size_t ws_size,
                              hipStream_t stream) {
    (void)in_sizes; (void)n_in; (void)out_size; (void)ws_size;
    const float* hidden = (const float*)d_in[0];
    const float* cosb   = (const float*)d_in[1];
    const float* sinb   = (const float*)d_in[2];
    // d_in[3] = attention_mask: causal, computed inline
    const float* q_w    = (const float*)d_in[4];
    const float* k_w    = (const float*)d_in[5];
    const float* v_w    = (const float*)d_in[6];
    const float* o_w    = (const float*)d_in[7];

    char* ws = (char*)d_ws;                                  // 104 MB used
    ushort_t* hb   = (ushort_t*)(ws);                        // [4096][2048] bf16 hidden
    ushort_t* wqkv = (ushort_t*)(ws + (16ull << 20));        // [4096][2048] bf16 q|k|v weights
    ushort_t* owb  = (ushort_t*)(ws + (32ull << 20));        // [2048][2048] bf16 o_w
    ushort_t* qkv  = (ushort_t*)(ws + (40ull << 20));        // [4096][4096] bf16 qkv proj
    ushort_t* attn = qkv;                                    // alias: qkv consumed before flash
    ushort_t* qb   = (ushort_t*)(ws + (72ull << 20));        // [2][16][2048][128]
    ushort_t* kb   = (ushort_t*)(ws + (88ull << 20));        // [2][8][2048][128]
    ushort_t* vt   = (ushort_t*)(ws + (96ull << 20));        // [2][8][128][2048]

    convert_bf16<<<8192, 256, 0, stream>>>((const f32x4*)hidden, (us4*)hb, 2097152);
    convert_bf16<<<4096, 256, 0, stream>>>((const f32x4*)q_w, (us4*)wqkv, 1048576);
    convert_bf16<<<2048, 256, 0, stream>>>((const f32x4*)k_w, (us4*)(wqkv + 2048 * 2048), 524288);
    convert_bf16<<<2048, 256, 0, stream>>>((const f32x4*)v_w, (us4*)(wqkv + 3072 * 2048), 524288);
    convert_bf16<<<4096, 256, 0, stream>>>((const f32x4*)o_w, (us4*)owb, 1048576);

    gemm_bt<ushort_t><<<dim3(32, 32), 256, 0, stream>>>(hb, wqkv, qkv, 4096, 4096, 2048);
    rope_norm<<<dim3(4096, 6), 256, 0, stream>>>(qkv, cosb, sinb, qb, kb);
    v_transpose<<<dim3(32, 2, 16), 256, 0, stream>>>(qkv, vt);
    flash_attn<<<dim3(32, 16, 2), 256, 0, stream>>>(qb, kb, vt, attn);
    gemm_bt<float><<<dim3(32, 16), 256, 0, stream>>>(attn, owb, (float*)d_out, 4096, 2048, 2048);
}

// Round 2
// 469.059 us; speedup vs baseline: 1.0591x; 1.0591x over previous
//
#include <hip/hip_runtime.h>

typedef unsigned short ushort_t;
typedef __bf16 bf16x8 __attribute__((ext_vector_type(8)));
typedef float f32x4 __attribute__((ext_vector_type(4)));
typedef unsigned int u32x4 __attribute__((ext_vector_type(4)));
typedef unsigned short us4 __attribute__((ext_vector_type(4)));
typedef unsigned short us8 __attribute__((ext_vector_type(8)));

#define DEVINL __device__ __forceinline__

DEVINL ushort_t f2bf(float f) {
    unsigned u = __float_as_uint(f);
    u += 0x7FFF + ((u >> 16) & 1);   // RNE
    return (ushort_t)(u >> 16);
}
DEVINL float bf2f(ushort_t h) { return __uint_as_float(((unsigned)h) << 16); }

DEVINL void gload_lds16(const void* g, void* l) {
    __builtin_amdgcn_global_load_lds(
        (const __attribute__((address_space(1))) void*)g,
        (__attribute__((address_space(3))) void*)l, 16, 0, 0);
}

DEVINL bf16x8 ld_frag(const ushort_t* p) {
    us8 v = *(const us8*)p;
    return __builtin_bit_cast(bf16x8, v);
}

// ---------------------------------------------------------------- convert
__global__ __launch_bounds__(256) void convert_bf16(const f32x4* __restrict__ in,
                                                    us4* __restrict__ out, int n4) {
    int i = blockIdx.x * 256 + threadIdx.x;
    if (i >= n4) return;
    f32x4 f = in[i];
    us4 o;
    o[0] = f2bf(f[0]); o[1] = f2bf(f[1]); o[2] = f2bf(f[2]); o[3] = f2bf(f[3]);
    out[i] = o;
}

// ---------------------------------------------------------------- GEMM C = A @ W^T
// A[M][K] bf16 row-major, W[N][K] bf16 row-major, C[M][N] (bf16 or f32).
// 128x128 tile, BK=32, 4 waves in 2x2, each wave 64x64 (4x4 of 16x16 MFMA).
template <typename OutT>
__global__ __launch_bounds__(256) void gemm_bt(const ushort_t* __restrict__ A,
                                               const ushort_t* __restrict__ W,
                                               OutT* __restrict__ C,
                                               int M, int N, int K) {
    __shared__ ushort_t As[128 * 32];
    __shared__ ushort_t Bs[128 * 32];
    const int t = threadIdx.x;
    const int w = t >> 6, lane = t & 63;
    const int quad = lane >> 4, l16 = lane & 15;
    const int bm = blockIdx.x * 128, bn = blockIdx.y * 128;
    const int wr = (w >> 1) * 64, wc = (w & 1) * 64;

    f32x4 acc[4][4];
#pragma unroll
    for (int i = 0; i < 4; i++)
#pragma unroll
        for (int j = 0; j < 4; j++) acc[i][j] = f32x4{0.f, 0.f, 0.f, 0.f};

    for (int k0 = 0; k0 < K; k0 += 32) {
        __syncthreads();
#pragma unroll
        for (int i = 0; i < 2; i++) {
            int u = i * 256 + t;          // 16B-chunk index; LDS dest = u*16 (lane-contiguous)
            int row = u >> 2;
            int ce = (u & 3) * 8;         // element offset within 32-elem row
            gload_lds16(A + (size_t)(bm + row) * K + k0 + ce, (char*)As + u * 16);
            gload_lds16(W + (size_t)(bn + row) * K + k0 + ce, (char*)Bs + u * 16);
        }
        __syncthreads();
        bf16x8 af[4], bf[4];
#pragma unroll
        for (int mt = 0; mt < 4; mt++)
            af[mt] = ld_frag(&As[(wr + mt * 16 + l16) * 32 + quad * 8]);
#pragma unroll
        for (int nt = 0; nt < 4; nt++)
            bf[nt] = ld_frag(&Bs[(wc + nt * 16 + l16) * 32 + quad * 8]);
#pragma unroll
        for (int mt = 0; mt < 4; mt++)
#pragma unroll
            for (int nt = 0; nt < 4; nt++)
                acc[mt][nt] = __builtin_amdgcn_mfma_f32_16x16x32_bf16(af[mt], bf[nt],
                                                                      acc[mt][nt], 0, 0, 0);
    }

#pragma unroll
    for (int mt = 0; mt < 4; mt++)
#pragma unroll
        for (int nt = 0; nt < 4; nt++) {
            int row = bm + wr + mt * 16 + quad * 4;
            int col = bn + wc + nt * 16 + l16;
#pragma unroll
            for (int r = 0; r < 4; r++) {
                float v = acc[mt][nt][r];
                if constexpr (sizeof(OutT) == 2)
                    C[(size_t)(row + r) * N + col] = (OutT)f2bf(v);
                else
                    C[(size_t)(row + r) * N + col] = v;
            }
        }
}

// ---------------------------------------------------------------- RoPE + l2norm
__global__ __launch_bounds__(256) void rope_norm(const ushort_t* __restrict__ qkv,
                                                 const float* __restrict__ cosb,
                                                 const float* __restrict__ sinb,
                                                 ushort_t* __restrict__ q,
                                                 ushort_t* __restrict__ k) {
    int row = blockIdx.x;                 // b*2048 + s
    int b = row >> 11, s = row & 2047;
    int w = threadIdx.x >> 6, lane = threadIdx.x & 63;
    int hh = blockIdx.y * 4 + w;          // 0..23
    const ushort_t* src = qkv + (size_t)row * 4096 + hh * 128;
    float x1 = bf2f(src[lane]);
    float x2 = bf2f(src[lane + 64]);
    float c = cosb[(size_t)row * 128 + lane];
    float sn = sinb[(size_t)row * 128 + lane];
    float y1 = x1 * c + x2 * sn;
    float y2 = x2 * c - x1 * sn;
    float ss = y1 * y1 + y2 * y2;
#pragma unroll
    for (int off = 1; off < 64; off <<= 1) ss += __shfl_xor(ss, off);
    float rinv = rsqrtf(ss * (1.0f / 128.0f) + 1e-6f);
    y1 *= rinv; y2 *= rinv;
    ushort_t* dst;
    if (hh < 16) dst = q + (((size_t)(b * 16 + hh)) * 2048 + s) * 128;
    else         dst = k + (((size_t)(b * 8 + hh - 16)) * 2048 + s) * 128;
    dst[lane] = f2bf(y1);
    dst[lane + 64] = f2bf(y2);
}

// ---------------------------------------------------------------- V transpose
__global__ __launch_bounds__(256) void v_transpose(const ushort_t* __restrict__ qkv,
                                                   ushort_t* __restrict__ vt) {
    __shared__ ushort_t tile[64 * 72];
    int t = threadIdx.x;
    int s0 = blockIdx.x * 64, d0 = blockIdx.y * 64, bh = blockIdx.z;
    int b = bh >> 3, kvh = bh & 7;
    {
        int sl = t >> 2, c = t & 3;
        const ushort_t* src = qkv + (size_t)(b * 2048 + s0 + sl) * 4096 + 3072 + kvh * 128 + d0 + c * 16;
        u32x4 v0 = *(const u32x4*)src;
        u32x4 v1 = *(const u32x4*)(src + 8);
        *(u32x4*)&tile[sl * 72 + c * 16] = v0;
        *(u32x4*)&tile[sl * 72 + c * 16 + 8] = v1;
    }
    __syncthreads();
    {
        int dl = t >> 2, c = t & 3;
        alignas(16) ushort_t tmp[16];
#pragma unroll
        for (int i = 0; i < 16; i++) tmp[i] = tile[(c * 16 + i) * 72 + dl];
        ushort_t* dst = vt + (size_t)(bh * 128 + d0 + dl) * 2048 + s0 + c * 16;
        *(u32x4*)dst = *(const u32x4*)&tmp[0];
        *(u32x4*)(dst + 8) = *(const u32x4*)&tmp[8];
    }
}

// ---------------------------------------------------------------- Flash attention (GQA-merged, fixed-max)
// Grid (32, NKV, B). Block handles BOTH q-heads of kv-group kvh for one q-tile
// of 64 rows. qi = 31 - blockIdx.x (heavy blocks dispatch first). 4 waves; wave
// w owns q-rows q0+16w..+15 for both heads. K/V fragments feed 2 MFMAs each.
// Fixed softmax max (q,k are l2-normed: |score*scale| <= 1 in log2-domain):
//   p = exp2(dot*C1 - C2), C1 = scale*log2(e), C2 = 1.45 (>= log2(e)).
// No running max, no in-loop cross-lane ops; l reduced once in epilogue.
__global__ __launch_bounds__(256) void flash_attn(const ushort_t* __restrict__ q,
                                                  const ushort_t* __restrict__ k,
                                                  const ushort_t* __restrict__ vt,
                                                  ushort_t* __restrict__ attn) {
    __shared__ ushort_t Ks[4 * 64 * 32];      // 16 KB  [qd][64][32]
    __shared__ ushort_t Vts[2 * 128 * 32];    // 16 KB  [ks][128][32]
    __shared__ ushort_t Ps[4 * 32 * 72];      // 18 KB  per-wave [head*16+row][72]
    const int t = threadIdx.x;
    const int w = t >> 6, lane = t & 63;
    const int quad = lane >> 4, l16 = lane & 15;
    const int qi = (int)gridDim.x - 1 - (int)blockIdx.x;   // reverse: heavy first
    const int q0 = qi * 64;
    const int kvh = blockIdx.y, b = blockIdx.z;
    const int h0 = kvh * 2;
    const size_t kbase = ((size_t)(b * 8 + kvh)) * 2048 * 128;
    const size_t vbase = ((size_t)(b * 8 + kvh)) * 128 * 2048;

    bf16x8 qf[2][4];
#pragma unroll
    for (int h = 0; h < 2; h++) {
        const size_t qbase = ((size_t)(b * 16 + h0 + h) * 2048 + q0 + w * 16 + l16) * 128;
#pragma unroll
        for (int qd = 0; qd < 4; qd++) {
            us8 v = *(const us8*)(q + qbase + qd * 32 + quad * 8);
            qf[h][qd] = __builtin_bit_cast(bf16x8, v);
        }
    }

    f32x4 o[2][8];
#pragma unroll
    for (int h = 0; h < 2; h++)
#pragma unroll
        for (int i = 0; i < 8; i++) o[h][i] = f32x4{0.f, 0.f, 0.f, 0.f};
    float lsum[2][4];
#pragma unroll
    for (int h = 0; h < 2; h++)
#pragma unroll
        for (int r = 0; r < 4; r++) lsum[h][r] = 0.f;

    const float C1 = 0.12751744f;   // (1/sqrt(128)) * log2(e)
    const float C2 = 1.45f;         // fixed max in log2 domain (>= log2(e))

    for (int jt = 0; jt <= qi; ++jt) {
        const int j0 = jt * 64;
        const bool diag = (jt == qi);
        __syncthreads();
#pragma unroll
        for (int i = 0; i < 4; i++) {           // stage K tile (16KB), k-blocked
            int u = i * 256 + t;
            int qd = u >> 8, rr = (u >> 2) & 63, c4 = u & 3;
            gload_lds16(k + kbase + (size_t)(j0 + rr) * 128 + qd * 32 + c4 * 8,
                        (char*)Ks + u * 16);
        }
#pragma unroll
        for (int i = 0; i < 4; i++) {           // stage Vt tile (16KB), k-blocked
            int u = i * 256 + t;
            int ks = u >> 9, dd = (u >> 2) & 127, c4 = u & 3;
            gload_lds16(vt + vbase + (size_t)dd * 2048 + j0 + ks * 32 + c4 * 8,
                        (char*)Vts + u * 16);
        }
        __syncthreads();

        // S = Q K^T for both heads; each kf feeds 2 MFMAs
        f32x4 sc[2][4];
#pragma unroll
        for (int h = 0; h < 2; h++)
#pragma unroll
            for (int c = 0; c < 4; c++) sc[h][c] = f32x4{0.f, 0.f, 0.f, 0.f};
#pragma unroll
        for (int c = 0; c < 4; c++)
#pragma unroll
            for (int qd = 0; qd < 4; qd++) {
                bf16x8 kf = ld_frag(&Ks[qd * 2048 + (c * 16 + l16) * 32 + quad * 8]);
                sc[0][c] = __builtin_amdgcn_mfma_f32_16x16x32_bf16(qf[0][qd], kf, sc[0][c], 0, 0, 0);
                sc[1][c] = __builtin_amdgcn_mfma_f32_16x16x32_bf16(qf[1][qd], kf, sc[1][c], 0, 0, 0);
            }

        // p = exp2(s*C1 - C2); mask only on the diagonal tile; accumulate l per-lane
#pragma unroll
        for (int c = 0; c < 4; c++)
#pragma unroll
            for (int r = 0; r < 4; r++) {
                float p0 = __builtin_amdgcn_exp2f(sc[0][c][r] * C1 - C2);
                float p1 = __builtin_amdgcn_exp2f(sc[1][c][r] * C1 - C2);
                if (diag) {
                    int kg = j0 + c * 16 + l16;
                    int qg = q0 + w * 16 + quad * 4 + r;
                    if (kg > qg) { p0 = 0.f; p1 = 0.f; }
                }
                lsum[0][r] += p0;
                lsum[1][r] += p1;
                Ps[w * 2304 + (quad * 4 + r) * 72 + c * 16 + l16] = f2bf(p0);
                Ps[w * 2304 + (16 + quad * 4 + r) * 72 + c * 16 + l16] = f2bf(p1);
            }

        // O += P V; each vf feeds 2 MFMAs
#pragma unroll
        for (int ks = 0; ks < 2; ks++) {
            bf16x8 pf0 = ld_frag(&Ps[w * 2304 + l16 * 72 + ks * 32 + quad * 8]);
            bf16x8 pf1 = ld_frag(&Ps[w * 2304 + (16 + l16) * 72 + ks * 32 + quad * 8]);
#pragma unroll
            for (int od = 0; od < 8; od++) {
                bf16x8 vf = ld_frag(&Vts[ks * 4096 + (od * 16 + l16) * 32 + quad * 8]);
                o[0][od] = __builtin_amdgcn_mfma_f32_16x16x32_bf16(pf0, vf, o[0][od], 0, 0, 0);
                o[1][od] = __builtin_amdgcn_mfma_f32_16x16x32_bf16(pf1, vf, o[1][od], 0, 0, 0);
            }
        }
    }

    // epilogue: one cross-lane reduce of l over the 16-lane column group
    float rl[2][4];
#pragma unroll
    for (int h = 0; h < 2; h++)
#pragma unroll
        for (int r = 0; r < 4; r++) {
            float s = lsum[h][r];
#pragma unroll
            for (int off = 1; off < 16; off <<= 1) s += __shfl_xor(s, off);
            rl[h][r] = 1.0f / s;
        }
#pragma unroll
    for (int h = 0; h < 2; h++) {
        const size_t obase = ((size_t)(b * 2048 + q0 + w * 16 + quad * 4)) * 2048 + (h0 + h) * 128;
#pragma unroll
        for (int od = 0; od < 8; od++)
#pragma unroll
            for (int r = 0; r < 4; r++)
                attn[obase + (size_t)r * 2048 + od * 16 + l16] = f2bf(o[h][od][r] * rl[h][r]);
    }
}

// ---------------------------------------------------------------- launch
extern "C" void kernel_launch(void* const* d_in, const int* in_sizes, int n_in,
                              void* d_out, int out_size, void* d_ws, size_t ws_size,
                              hipStream_t stream) {
    (void)in_sizes; (void)n_in; (void)out_size; (void)ws_size;
    const float* hidden = (const float*)d_in[0];
    const float* cosb   = (const float*)d_in[1];
    const float* sinb   = (const float*)d_in[2];
    // d_in[3] = attention_mask: causal, computed inline
    const float* q_w    = (const float*)d_in[4];
    const float* k_w    = (const float*)d_in[5];
    const float* v_w    = (const float*)d_in[6];
    const float* o_w    = (const float*)d_in[7];

    char* ws = (char*)d_ws;                                  // 104 MB used
    ushort_t* hb   = (ushort_t*)(ws);                        // [4096][2048] bf16 hidden
    ushort_t* wqkv = (ushort_t*)(ws + (16ull << 20));        // [4096][2048] bf16 q|k|v weights
    ushort_t* owb  = (ushort_t*)(ws + (32ull << 20));        // [2048][2048] bf16 o_w
    ushort_t* qkv  = (ushort_t*)(ws + (40ull << 20));        // [4096][4096] bf16 qkv proj
    ushort_t* attn = qkv;                                    // alias: qkv consumed before flash
    ushort_t* qb   = (ushort_t*)(ws + (72ull << 20));        // [2][16][2048][128]
    ushort_t* kb   = (ushort_t*)(ws + (88ull << 20));        // [2][8][2048][128]
    ushort_t* vt   = (ushort_t*)(ws + (96ull << 20));        // [2][8][128][2048]

    convert_bf16<<<8192, 256, 0, stream>>>((const f32x4*)hidden, (us4*)hb, 2097152);
    convert_bf16<<<4096, 256, 0, stream>>>((const f32x4*)q_w, (us4*)wqkv, 1048576);
    convert_bf16<<<2048, 256, 0, stream>>>((const f32x4*)k_w, (us4*)(wqkv + 2048 * 2048), 524288);
    convert_bf16<<<2048, 256, 0, stream>>>((const f32x4*)v_w, (us4*)(wqkv + 3072 * 2048), 524288);
    convert_bf16<<<4096, 256, 0, stream>>>((const f32x4*)o_w, (us4*)owb, 1048576);

    gemm_bt<ushort_t><<<dim3(32, 32), 256, 0, stream>>>(hb, wqkv, qkv, 4096, 4096, 2048);
    rope_norm<<<dim3(4096, 6), 256, 0, stream>>>(qkv, cosb, sinb, qb, kb);
    v_transpose<<<dim3(32, 2, 16), 256, 0, stream>>>(qkv, vt);
    flash_attn<<<dim3(32, 8, 2), 256, 0, stream>>>(qb, kb, vt, attn);
    gemm_bt<float><<<dim3(32, 16), 256, 0, stream>>>(attn, owb, (float*)d_out, 4096, 2048, 2048);
}

// Round 3
// 401.063 us; speedup vs baseline: 1.2387x; 1.1695x over previous
//
#include <hip/hip_runtime.h>

typedef unsigned short ushort_t;
typedef __bf16 bf16x8 __attribute__((ext_vector_type(8)));
typedef float f32x4 __attribute__((ext_vector_type(4)));
typedef unsigned int u32x4 __attribute__((ext_vector_type(4)));
typedef unsigned short us4 __attribute__((ext_vector_type(4)));
typedef unsigned short us8 __attribute__((ext_vector_type(8)));

#define DEVINL __device__ __forceinline__

DEVINL ushort_t f2bf(float f) {
    unsigned u = __float_as_uint(f);
    u += 0x7FFF + ((u >> 16) & 1);   // RNE
    return (ushort_t)(u >> 16);
}
DEVINL float bf2f(ushort_t h) { return __uint_as_float(((unsigned)h) << 16); }

DEVINL void gload_lds16(const void* g, void* l) {
    __builtin_amdgcn_global_load_lds(
        (const __attribute__((address_space(1))) void*)g,
        (__attribute__((address_space(3))) void*)l, 16, 0, 0);
}

DEVINL bf16x8 ld_frag(const ushort_t* p) {
    us8 v = *(const us8*)p;
    return __builtin_bit_cast(bf16x8, v);
}

// ---------------------------------------------------------------- convert
__global__ __launch_bounds__(256) void convert_bf16(const f32x4* __restrict__ in,
                                                    us4* __restrict__ out, int n4) {
    int i = blockIdx.x * 256 + threadIdx.x;
    if (i >= n4) return;
    f32x4 f = in[i];
    us4 o;
    o[0] = f2bf(f[0]); o[1] = f2bf(f[1]); o[2] = f2bf(f[2]); o[3] = f2bf(f[3]);
    out[i] = o;
}

// ---------------------------------------------------------------- GEMM C = A @ W^T
// A[M][K] bf16 row-major, W[N][K] bf16 row-major, C[M][N] (bf16 or f32).
// 128x128 tile, BK=32, 4 waves in 2x2, each wave 64x64 (4x4 of 16x16 MFMA).
template <typename OutT>
__global__ __launch_bounds__(256) void gemm_bt(const ushort_t* __restrict__ A,
                                               const ushort_t* __restrict__ W,
                                               OutT* __restrict__ C,
                                               int M, int N, int K) {
    __shared__ ushort_t As[128 * 32];
    __shared__ ushort_t Bs[128 * 32];
    const int t = threadIdx.x;
    const int w = t >> 6, lane = t & 63;
    const int quad = lane >> 4, l16 = lane & 15;
    const int bm = blockIdx.x * 128, bn = blockIdx.y * 128;
    const int wr = (w >> 1) * 64, wc = (w & 1) * 64;

    f32x4 acc[4][4];
#pragma unroll
    for (int i = 0; i < 4; i++)
#pragma unroll
        for (int j = 0; j < 4; j++) acc[i][j] = f32x4{0.f, 0.f, 0.f, 0.f};

    for (int k0 = 0; k0 < K; k0 += 32) {
        __syncthreads();
#pragma unroll
        for (int i = 0; i < 2; i++) {
            int u = i * 256 + t;          // 16B-chunk index; LDS dest = u*16 (lane-contiguous)
            int row = u >> 2;
            int ce = (u & 3) * 8;         // element offset within 32-elem row
            gload_lds16(A + (size_t)(bm + row) * K + k0 + ce, (char*)As + u * 16);
            gload_lds16(W + (size_t)(bn + row) * K + k0 + ce, (char*)Bs + u * 16);
        }
        __syncthreads();
        bf16x8 af[4], bf[4];
#pragma unroll
        for (int mt = 0; mt < 4; mt++)
            af[mt] = ld_frag(&As[(wr + mt * 16 + l16) * 32 + quad * 8]);
#pragma unroll
        for (int nt = 0; nt < 4; nt++)
            bf[nt] = ld_frag(&Bs[(wc + nt * 16 + l16) * 32 + quad * 8]);
#pragma unroll
        for (int mt = 0; mt < 4; mt++)
#pragma unroll
            for (int nt = 0; nt < 4; nt++)
                acc[mt][nt] = __builtin_amdgcn_mfma_f32_16x16x32_bf16(af[mt], bf[nt],
                                                                      acc[mt][nt], 0, 0, 0);
    }

#pragma unroll
    for (int mt = 0; mt < 4; mt++)
#pragma unroll
        for (int nt = 0; nt < 4; nt++) {
            int row = bm + wr + mt * 16 + quad * 4;
            int col = bn + wc + nt * 16 + l16;
#pragma unroll
            for (int r = 0; r < 4; r++) {
                float v = acc[mt][nt][r];
                if constexpr (sizeof(OutT) == 2)
                    C[(size_t)(row + r) * N + col] = (OutT)f2bf(v);
                else
                    C[(size_t)(row + r) * N + col] = v;
            }
        }
}

// ---------------------------------------------------------------- RoPE + l2norm
__global__ __launch_bounds__(256) void rope_norm(const ushort_t* __restrict__ qkv,
                                                 const float* __restrict__ cosb,
                                                 const float* __restrict__ sinb,
                                                 ushort_t* __restrict__ q,
                                                 ushort_t* __restrict__ k) {
    int row = blockIdx.x;                 // b*2048 + s
    int b = row >> 11, s = row & 2047;
    int w = threadIdx.x >> 6, lane = threadIdx.x & 63;
    int hh = blockIdx.y * 4 + w;          // 0..23
    const ushort_t* src = qkv + (size_t)row * 4096 + hh * 128;
    float x1 = bf2f(src[lane]);
    float x2 = bf2f(src[lane + 64]);
    float c = cosb[(size_t)row * 128 + lane];
    float sn = sinb[(size_t)row * 128 + lane];
    float y1 = x1 * c + x2 * sn;
    float y2 = x2 * c - x1 * sn;
    float ss = y1 * y1 + y2 * y2;
#pragma unroll
    for (int off = 1; off < 64; off <<= 1) ss += __shfl_xor(ss, off);
    float rinv = rsqrtf(ss * (1.0f / 128.0f) + 1e-6f);
    y1 *= rinv; y2 *= rinv;
    ushort_t* dst;
    if (hh < 16) dst = q + (((size_t)(b * 16 + hh)) * 2048 + s) * 128;
    else         dst = k + (((size_t)(b * 8 + hh - 16)) * 2048 + s) * 128;
    dst[lane] = f2bf(y1);
    dst[lane + 64] = f2bf(y2);
}

// ---------------------------------------------------------------- V transpose
__global__ __launch_bounds__(256) void v_transpose(const ushort_t* __restrict__ qkv,
                                                   ushort_t* __restrict__ vt) {
    __shared__ ushort_t tile[64 * 72];
    int t = threadIdx.x;
    int s0 = blockIdx.x * 64, d0 = blockIdx.y * 64, bh = blockIdx.z;
    int b = bh >> 3, kvh = bh & 7;
    {
        int sl = t >> 2, c = t & 3;
        const ushort_t* src = qkv + (size_t)(b * 2048 + s0 + sl) * 4096 + 3072 + kvh * 128 + d0 + c * 16;
        u32x4 v0 = *(const u32x4*)src;
        u32x4 v1 = *(const u32x4*)(src + 8);
        *(u32x4*)&tile[sl * 72 + c * 16] = v0;
        *(u32x4*)&tile[sl * 72 + c * 16 + 8] = v1;
    }
    __syncthreads();
    {
        int dl = t >> 2, c = t & 3;
        alignas(16) ushort_t tmp[16];
#pragma unroll
        for (int i = 0; i < 16; i++) tmp[i] = tile[(c * 16 + i) * 72 + dl];
        ushort_t* dst = vt + (size_t)(bh * 128 + d0 + dl) * 2048 + s0 + c * 16;
        *(u32x4*)dst = *(const u32x4*)&tmp[0];
        *(u32x4*)(dst + 8) = *(const u32x4*)&tmp[8];
    }
}

// ---------------------------------------------------------------- Flash attention
// (GQA-merged, fixed-max, PAIRED q-tiles, double-buffered async staging)
// Grid (16, NKV, B). Block p handles q-tiles qi = 31-p then qi = p sequentially:
// exactly 33 kv-tile-units per block -> perfect balance at 1 block/CU.
// K/V staged via global_load_lds into alternating 32KB buffers; prefetch for
// tile s+1 is issued right after the barrier for tile s and completes during
// compute, so the vmcnt(0) drain at the next barrier is ~free. One barrier/tile.
__global__ __launch_bounds__(256) void flash_attn(const ushort_t* __restrict__ q,
                                                  const ushort_t* __restrict__ k,
                                                  const ushort_t* __restrict__ vt,
                                                  ushort_t* __restrict__ attn) {
    __shared__ ushort_t Ks[2][4 * 64 * 32];      // 2 x 16 KB  [qd][64][32]
    __shared__ ushort_t Vts[2][2 * 128 * 32];    // 2 x 16 KB  [ks][128][32]
    __shared__ ushort_t Ps[4 * 32 * 72];         // 18 KB per-wave [head*16+row][72]
    const int t = threadIdx.x;
    const int w = t >> 6, lane = t & 63;
    const int quad = lane >> 4, l16 = lane & 15;
    const int p = blockIdx.x;                    // 0..15
    const int kvh = blockIdx.y, b = blockIdx.z;
    const int h0 = kvh * 2;
    const size_t kbase = ((size_t)(b * 8 + kvh)) * 2048 * 128;
    const size_t vbase = ((size_t)(b * 8 + kvh)) * 128 * 2048;

    const float C1 = 0.12751744f;   // (1/sqrt(128)) * log2(e)
    const float C2 = 1.45f;         // fixed max in log2 domain

    auto stage = [&](int j0, int buf) {
#pragma unroll
        for (int i = 0; i < 4; i++) {            // K tile (16KB), k-blocked
            int u = i * 256 + t;
            int qd = u >> 8, rr = (u >> 2) & 63, c4 = u & 3;
            gload_lds16(k + kbase + (size_t)(j0 + rr) * 128 + qd * 32 + c4 * 8,
                        (char*)Ks[buf] + u * 16);
        }
#pragma unroll
        for (int i = 0; i < 4; i++) {            // Vt tile (16KB), k-blocked
            int u = i * 256 + t;
            int ks = u >> 9, dd = (u >> 2) & 127, c4 = u & 3;
            gload_lds16(vt + vbase + (size_t)dd * 2048 + j0 + ks * 32 + c4 * 8,
                        (char*)Vts[buf] + u * 16);
        }
    };

    const int qtile0 = 31 - p;                   // heavy pass first
    stage(0, 0);
    int sbuf = 0;

    for (int pass = 0; pass < 2; ++pass) {
        const int qi = pass ? p : qtile0;
        const int q0 = qi * 64;

        bf16x8 qf[2][4];
#pragma unroll
        for (int h = 0; h < 2; h++) {
            const size_t qbase = ((size_t)(b * 16 + h0 + h) * 2048 + q0 + w * 16 + l16) * 128;
#pragma unroll
            for (int qd = 0; qd < 4; qd++) {
                us8 v = *(const us8*)(q + qbase + qd * 32 + quad * 8);
                qf[h][qd] = __builtin_bit_cast(bf16x8, v);
            }
        }

        f32x4 o[2][8];
#pragma unroll
        for (int h = 0; h < 2; h++)
#pragma unroll
            for (int i = 0; i < 8; i++) o[h][i] = f32x4{0.f, 0.f, 0.f, 0.f};
        float lsum[2][4];
#pragma unroll
        for (int h = 0; h < 2; h++)
#pragma unroll
            for (int r = 0; r < 4; r++) lsum[h][r] = 0.f;

        for (int jt = 0; jt <= qi; ++jt) {
            const int j0 = jt * 64;
            const bool diag = (jt == qi);
            __syncthreads();                     // drains this wave's prefetch DMA
            // issue prefetch for the next tile in the stream (crosses pass boundary)
            const int nb = sbuf ^ 1;
            if (jt < qi)            stage((jt + 1) * 64, nb);
            else if (pass == 0)     stage(0, nb);
            const ushort_t* Kb = Ks[sbuf];
            const ushort_t* Vb = Vts[sbuf];
            sbuf = nb;

            // S = Q K^T for both heads; each kf feeds 2 MFMAs
            f32x4 sc[2][4];
#pragma unroll
            for (int h = 0; h < 2; h++)
#pragma unroll
                for (int c = 0; c < 4; c++) sc[h][c] = f32x4{0.f, 0.f, 0.f, 0.f};
#pragma unroll
            for (int c = 0; c < 4; c++)
#pragma unroll
                for (int qd = 0; qd < 4; qd++) {
                    bf16x8 kf = ld_frag(&Kb[qd * 2048 + (c * 16 + l16) * 32 + quad * 8]);
                    sc[0][c] = __builtin_amdgcn_mfma_f32_16x16x32_bf16(qf[0][qd], kf, sc[0][c], 0, 0, 0);
                    sc[1][c] = __builtin_amdgcn_mfma_f32_16x16x32_bf16(qf[1][qd], kf, sc[1][c], 0, 0, 0);
                }

            // p = exp2(s*C1 - C2); mask only on the diagonal tile
#pragma unroll
            for (int c = 0; c < 4; c++)
#pragma unroll
                for (int r = 0; r < 4; r++) {
                    float p0 = __builtin_amdgcn_exp2f(sc[0][c][r] * C1 - C2);
                    float p1 = __builtin_amdgcn_exp2f(sc[1][c][r] * C1 - C2);
                    if (diag) {
                        int kg = j0 + c * 16 + l16;
                        int qg = q0 + w * 16 + quad * 4 + r;
                        if (kg > qg) { p0 = 0.f; p1 = 0.f; }
                    }
                    lsum[0][r] += p0;
                    lsum[1][r] += p1;
                    Ps[w * 2304 + (quad * 4 + r) * 72 + c * 16 + l16] = f2bf(p0);
                    Ps[w * 2304 + (16 + quad * 4 + r) * 72 + c * 16 + l16] = f2bf(p1);
                }

            // O += P V; each vf feeds 2 MFMAs
#pragma unroll
            for (int ks = 0; ks < 2; ks++) {
                bf16x8 pf0 = ld_frag(&Ps[w * 2304 + l16 * 72 + ks * 32 + quad * 8]);
                bf16x8 pf1 = ld_frag(&Ps[w * 2304 + (16 + l16) * 72 + ks * 32 + quad * 8]);
#pragma unroll
                for (int od = 0; od < 8; od++) {
                    bf16x8 vf = ld_frag(&Vb[ks * 4096 + (od * 16 + l16) * 32 + quad * 8]);
                    o[0][od] = __builtin_amdgcn_mfma_f32_16x16x32_bf16(pf0, vf, o[0][od], 0, 0, 0);
                    o[1][od] = __builtin_amdgcn_mfma_f32_16x16x32_bf16(pf1, vf, o[1][od], 0, 0, 0);
                }
            }
        }

        // epilogue for this q-tile
        float rl[2][4];
#pragma unroll
        for (int h = 0; h < 2; h++)
#pragma unroll
            for (int r = 0; r < 4; r++) {
                float s = lsum[h][r];
#pragma unroll
                for (int off = 1; off < 16; off <<= 1) s += __shfl_xor(s, off);
                rl[h][r] = 1.0f / s;
            }
#pragma unroll
        for (int h = 0; h < 2; h++) {
            const size_t obase = ((size_t)(b * 2048 + q0 + w * 16 + quad * 4)) * 2048 + (h0 + h) * 128;
#pragma unroll
            for (int od = 0; od < 8; od++)
#pragma unroll
                for (int r = 0; r < 4; r++)
                    attn[obase + (size_t)r * 2048 + od * 16 + l16] = f2bf(o[h][od][r] * rl[h][r]);
        }
    }
}

// ---------------------------------------------------------------- launch
extern "C" void kernel_launch(void* const* d_in, const int* in_sizes, int n_in,
                              void* d_out, int out_size, void* d_ws, size_t ws_size,
                              hipStream_t stream) {
    (void)in_sizes; (void)n_in; (void)out_size; (void)ws_size;
    const float* hidden = (const float*)d_in[0];
    const float* cosb   = (const float*)d_in[1];
    const float* sinb   = (const float*)d_in[2];
    // d_in[3] = attention_mask: causal, computed inline
    const float* q_w    = (const float*)d_in[4];
    const float* k_w    = (const float*)d_in[5];
    const float* v_w    = (const float*)d_in[6];
    const float* o_w    = (const float*)d_in[7];

    char* ws = (char*)d_ws;                                  // 104 MB used
    ushort_t* hb   = (ushort_t*)(ws);                        // [4096][2048] bf16 hidden
    ushort_t* wqkv = (ushort_t*)(ws + (16ull << 20));        // [4096][2048] bf16 q|k|v weights
    ushort_t* owb  = (ushort_t*)(ws + (32ull << 20));        // [2048][2048] bf16 o_w
    ushort_t* qkv  = (ushort_t*)(ws + (40ull << 20));        // [4096][4096] bf16 qkv proj
    ushort_t* attn = qkv;                                    // alias: qkv consumed before flash
    ushort_t* qb   = (ushort_t*)(ws + (72ull << 20));        // [2][16][2048][128]
    ushort_t* kb   = (ushort_t*)(ws + (88ull << 20));        // [2][8][2048][128]
    ushort_t* vt   = (ushort_t*)(ws + (96ull << 20));        // [2][8][128][2048]

    convert_bf16<<<8192, 256, 0, stream>>>((const f32x4*)hidden, (us4*)hb, 2097152);
    convert_bf16<<<4096, 256, 0, stream>>>((const f32x4*)q_w, (us4*)wqkv, 1048576);
    convert_bf16<<<2048, 256, 0, stream>>>((const f32x4*)k_w, (us4*)(wqkv + 2048 * 2048), 524288);
    convert_bf16<<<2048, 256, 0, stream>>>((const f32x4*)v_w, (us4*)(wqkv + 3072 * 2048), 524288);
    convert_bf16<<<4096, 256, 0, stream>>>((const f32x4*)o_w, (us4*)owb, 1048576);

    gemm_bt<ushort_t><<<dim3(32, 32), 256, 0, stream>>>(hb, wqkv, qkv, 4096, 4096, 2048);
    rope_norm<<<dim3(4096, 6), 256, 0, stream>>>(qkv, cosb, sinb, qb, kb);
    v_transpose<<<dim3(32, 2, 16), 256, 0, stream>>>(qkv, vt);
    flash_attn<<<dim3(16, 8, 2), 256, 0, stream>>>(qb, kb, vt, attn);
    gemm_bt<float><<<dim3(32, 16), 256, 0, stream>>>(attn, owb, (float*)d_out, 4096, 2048, 2048);
}

// Round 4
// 380.297 us; speedup vs baseline: 1.3063x; 1.0546x over previous
//
#include <hip/hip_runtime.h>

typedef unsigned short ushort_t;
typedef __bf16 bf16x8 __attribute__((ext_vector_type(8)));
typedef float f32x4 __attribute__((ext_vector_type(4)));
typedef unsigned int u32x4 __attribute__((ext_vector_type(4)));
typedef unsigned short us4 __attribute__((ext_vector_type(4)));
typedef unsigned short us8 __attribute__((ext_vector_type(8)));

#define DEVINL __device__ __forceinline__

DEVINL ushort_t f2bf(float f) {
    unsigned u = __float_as_uint(f);
    u += 0x7FFF + ((u >> 16) & 1);   // RNE
    return (ushort_t)(u >> 16);
}
DEVINL float bf2f(ushort_t h) { return __uint_as_float(((unsigned)h) << 16); }

DEVINL void gload_lds16(const void* g, void* l) {
    __builtin_amdgcn_global_load_lds(
        (const __attribute__((address_space(1))) void*)g,
        (__attribute__((address_space(3))) void*)l, 16, 0, 0);
}

DEVINL bf16x8 ld_frag(const ushort_t* p) {
    us8 v = *(const us8*)p;
    return __builtin_bit_cast(bf16x8, v);
}

// ---------------------------------------------------------------- convert
__global__ __launch_bounds__(256) void convert_bf16(const f32x4* __restrict__ in,
                                                    us4* __restrict__ out, int n4) {
    int i = blockIdx.x * 256 + threadIdx.x;
    if (i >= n4) return;
    f32x4 f = in[i];
    us4 o;
    o[0] = f2bf(f[0]); o[1] = f2bf(f[1]); o[2] = f2bf(f[2]); o[3] = f2bf(f[3]);
    out[i] = o;
}

// ---------------------------------------------------------------- GEMM C = A @ W^T
// A[M][K] bf16 row-major, W[N][K] bf16 row-major, C[M][N] (bf16 or f32).
// 128x128 tile, BK=32, 4 waves 2x2, wave 64x64 (4x4 of 16x16x32 MFMA).
// Single-barrier K-loop: barrier -> DMA-prefetch next tile into buf^1 ->
// compute current buf. XOR chunk swizzle c^((row>>1)&3) kills the 8-way
// bank concentration of row*64B+quad*16B fragment reads (DMA dest stays
// lane-contiguous; only global source addresses are permuted).
template <typename OutT>
__global__ __launch_bounds__(256) void gemm_bt(const ushort_t* __restrict__ A,
                                               const ushort_t* __restrict__ W,
                                               OutT* __restrict__ C,
                                               int M, int N, int K) {
    __shared__ ushort_t As[2][128 * 32];
    __shared__ ushort_t Bs[2][128 * 32];
    const int t = threadIdx.x;
    const int w = t >> 6, lane = t & 63;
    const int quad = lane >> 4, l16 = lane & 15;
    const int sw = (l16 >> 1) & 3;               // fragment-read chunk swizzle
    const int bm = blockIdx.x * 128, bn = blockIdx.y * 128;
    const int wr = (w >> 1) * 64, wc = (w & 1) * 64;

    f32x4 acc[4][4];
#pragma unroll
    for (int i = 0; i < 4; i++)
#pragma unroll
        for (int j = 0; j < 4; j++) acc[i][j] = f32x4{0.f, 0.f, 0.f, 0.f};

    auto stage = [&](int k0, int buf) {
#pragma unroll
        for (int i = 0; i < 2; i++) {
            int u = i * 256 + t;                 // 16B-chunk; LDS dest = u*16
            int row = u >> 2;
            int ce = ((u & 3) ^ ((row >> 1) & 3)) * 8;   // swizzled source chunk
            gload_lds16(A + (size_t)(bm + row) * K + k0 + ce, (char*)As[buf] + u * 16);
            gload_lds16(W + (size_t)(bn + row) * K + k0 + ce, (char*)Bs[buf] + u * 16);
        }
    };

    stage(0, 0);
    int sbuf = 0;
    for (int k0 = 0; k0 < K; k0 += 32) {
        __syncthreads();
        const int nb = sbuf ^ 1;
        if (k0 + 32 < K) stage(k0 + 32, nb);
        const ushort_t* Ab = As[sbuf];
        const ushort_t* Bb = Bs[sbuf];
        sbuf = nb;
        bf16x8 af[4], bf[4];
#pragma unroll
        for (int mt = 0; mt < 4; mt++)
            af[mt] = ld_frag(&Ab[(wr + mt * 16 + l16) * 32 + (quad ^ sw) * 8]);
#pragma unroll
        for (int nt = 0; nt < 4; nt++)
            bf[nt] = ld_frag(&Bb[(wc + nt * 16 + l16) * 32 + (quad ^ sw) * 8]);
#pragma unroll
        for (int mt = 0; mt < 4; mt++)
#pragma unroll
            for (int nt = 0; nt < 4; nt++)
                acc[mt][nt] = __builtin_amdgcn_mfma_f32_16x16x32_bf16(af[mt], bf[nt],
                                                                      acc[mt][nt], 0, 0, 0);
    }

#pragma unroll
    for (int mt = 0; mt < 4; mt++)
#pragma unroll
        for (int nt = 0; nt < 4; nt++) {
            int row = bm + wr + mt * 16 + quad * 4;
            int col = bn + wc + nt * 16 + l16;
#pragma unroll
            for (int r = 0; r < 4; r++) {
                float v = acc[mt][nt][r];
                if constexpr (sizeof(OutT) == 2)
                    C[(size_t)(row + r) * N + col] = (OutT)f2bf(v);
                else
                    C[(size_t)(row + r) * N + col] = v;
            }
        }
}

// ---------------------------------------------------------------- RoPE + l2norm
__global__ __launch_bounds__(256) void rope_norm(const ushort_t* __restrict__ qkv,
                                                 const float* __restrict__ cosb,
                                                 const float* __restrict__ sinb,
                                                 ushort_t* __restrict__ q,
                                                 ushort_t* __restrict__ k) {
    int row = blockIdx.x;                 // b*2048 + s
    int b = row >> 11, s = row & 2047;
    int w = threadIdx.x >> 6, lane = threadIdx.x & 63;
    int hh = blockIdx.y * 4 + w;          // 0..23
    const ushort_t* src = qkv + (size_t)row * 4096 + hh * 128;
    float x1 = bf2f(src[lane]);
    float x2 = bf2f(src[lane + 64]);
    float c = cosb[(size_t)row * 128 + lane];
    float sn = sinb[(size_t)row * 128 + lane];
    float y1 = x1 * c + x2 * sn;
    float y2 = x2 * c - x1 * sn;
    float ss = y1 * y1 + y2 * y2;
#pragma unroll
    for (int off = 1; off < 64; off <<= 1) ss += __shfl_xor(ss, off);
    float rinv = rsqrtf(ss * (1.0f / 128.0f) + 1e-6f);
    y1 *= rinv; y2 *= rinv;
    ushort_t* dst;
    if (hh < 16) dst = q + (((size_t)(b * 16 + hh)) * 2048 + s) * 128;
    else         dst = k + (((size_t)(b * 8 + hh - 16)) * 2048 + s) * 128;
    dst[lane] = f2bf(y1);
    dst[lane + 64] = f2bf(y2);
}

// ---------------------------------------------------------------- V transpose
__global__ __launch_bounds__(256) void v_transpose(const ushort_t* __restrict__ qkv,
                                                   ushort_t* __restrict__ vt) {
    __shared__ ushort_t tile[64 * 72];
    int t = threadIdx.x;
    int s0 = blockIdx.x * 64, d0 = blockIdx.y * 64, bh = blockIdx.z;
    int b = bh >> 3, kvh = bh & 7;
    {
        int sl = t >> 2, c = t & 3;
        const ushort_t* src = qkv + (size_t)(b * 2048 + s0 + sl) * 4096 + 3072 + kvh * 128 + d0 + c * 16;
        u32x4 v0 = *(const u32x4*)src;
        u32x4 v1 = *(const u32x4*)(src + 8);
        *(u32x4*)&tile[sl * 72 + c * 16] = v0;
        *(u32x4*)&tile[sl * 72 + c * 16 + 8] = v1;
    }
    __syncthreads();
    {
        int dl = t >> 2, c = t & 3;
        alignas(16) ushort_t tmp[16];
#pragma unroll
        for (int i = 0; i < 16; i++) tmp[i] = tile[(c * 16 + i) * 72 + dl];
        ushort_t* dst = vt + (size_t)(bh * 128 + d0 + dl) * 2048 + s0 + c * 16;
        *(u32x4*)dst = *(const u32x4*)&tmp[0];
        *(u32x4*)(dst + 8) = *(const u32x4*)&tmp[8];
    }
}

// ---------------------------------------------------------------- Flash attention
// (GQA-merged, fixed-max, paired q-tiles, dbuf async staging, bank-swizzled)
__global__ __launch_bounds__(256) void flash_attn(const ushort_t* __restrict__ q,
                                                  const ushort_t* __restrict__ k,
                                                  const ushort_t* __restrict__ vt,
                                                  ushort_t* __restrict__ attn) {
    __shared__ ushort_t Ks[2][4 * 64 * 32];      // 2 x 16 KB  [qd][64][32]
    __shared__ ushort_t Vts[2][2 * 128 * 32];    // 2 x 16 KB  [ks][128][32]
    __shared__ ushort_t Ps[4 * 32 * 72];         // 18 KB per-wave [head*16+row][72]
    const int t = threadIdx.x;
    const int w = t >> 6, lane = t & 63;
    const int quad = lane >> 4, l16 = lane & 15;
    const int sw = (l16 >> 1) & 3;
    const int p = blockIdx.x;                    // 0..15
    const int kvh = blockIdx.y, b = blockIdx.z;
    const int h0 = kvh * 2;
    const size_t kbase = ((size_t)(b * 8 + kvh)) * 2048 * 128;
    const size_t vbase = ((size_t)(b * 8 + kvh)) * 128 * 2048;

    const float C1 = 0.12751744f;   // (1/sqrt(128)) * log2(e)
    const float C2 = 1.45f;         // fixed max in log2 domain

    auto stage = [&](int j0, int buf) {
#pragma unroll
        for (int i = 0; i < 4; i++) {            // K tile (16KB), k-blocked
            int u = i * 256 + t;
            int qd = u >> 8, rr = (u >> 2) & 63;
            int c4 = ((u & 3) ^ ((rr >> 1) & 3)) * 8;
            gload_lds16(k + kbase + (size_t)(j0 + rr) * 128 + qd * 32 + c4,
                        (char*)Ks[buf] + u * 16);
        }
#pragma unroll
        for (int i = 0; i < 4; i++) {            // Vt tile (16KB), k-blocked
            int u = i * 256 + t;
            int ks = u >> 9, dd = (u >> 2) & 127;
            int c4 = ((u & 3) ^ ((dd >> 1) & 3)) * 8;
            gload_lds16(vt + vbase + (size_t)dd * 2048 + j0 + ks * 32 + c4,
                        (char*)Vts[buf] + u * 16);
        }
    };

    const int qtile0 = 31 - p;                   // heavy pass first
    stage(0, 0);
    int sbuf = 0;

    for (int pass = 0; pass < 2; ++pass) {
        const int qi = pass ? p : qtile0;
        const int q0 = qi * 64;

        bf16x8 qf[2][4];
#pragma unroll
        for (int h = 0; h < 2; h++) {
            const size_t qbase = ((size_t)(b * 16 + h0 + h) * 2048 + q0 + w * 16 + l16) * 128;
#pragma unroll
            for (int qd = 0; qd < 4; qd++) {
                us8 v = *(const us8*)(q + qbase + qd * 32 + quad * 8);
                qf[h][qd] = __builtin_bit_cast(bf16x8, v);
            }
        }

        f32x4 o[2][8];
#pragma unroll
        for (int h = 0; h < 2; h++)
#pragma unroll
            for (int i = 0; i < 8; i++) o[h][i] = f32x4{0.f, 0.f, 0.f, 0.f};
        float lsum[2][4];
#pragma unroll
        for (int h = 0; h < 2; h++)
#pragma unroll
            for (int r = 0; r < 4; r++) lsum[h][r] = 0.f;

        for (int jt = 0; jt <= qi; ++jt) {
            const int j0 = jt * 64;
            const bool diag = (jt == qi);
            __syncthreads();                     // drains this wave's prefetch DMA
            const int nb = sbuf ^ 1;
            if (jt < qi)            stage((jt + 1) * 64, nb);
            else if (pass == 0)     stage(0, nb);
            const ushort_t* Kb = Ks[sbuf];
            const ushort_t* Vb = Vts[sbuf];
            sbuf = nb;

            // S = Q K^T for both heads; each kf feeds 2 MFMAs
            f32x4 sc[2][4];
#pragma unroll
            for (int h = 0; h < 2; h++)
#pragma unroll
                for (int c = 0; c < 4; c++) sc[h][c] = f32x4{0.f, 0.f, 0.f, 0.f};
#pragma unroll
            for (int c = 0; c < 4; c++)
#pragma unroll
                for (int qd = 0; qd < 4; qd++) {
                    bf16x8 kf = ld_frag(&Kb[qd * 2048 + (c * 16 + l16) * 32 + (quad ^ sw) * 8]);
                    sc[0][c] = __builtin_amdgcn_mfma_f32_16x16x32_bf16(qf[0][qd], kf, sc[0][c], 0, 0, 0);
                    sc[1][c] = __builtin_amdgcn_mfma_f32_16x16x32_bf16(qf[1][qd], kf, sc[1][c], 0, 0, 0);
                }

            // p = exp2(s*C1 - C2); mask only on the diagonal tile
#pragma unroll
            for (int c = 0; c < 4; c++)
#pragma unroll
                for (int r = 0; r < 4; r++) {
                    float p0 = __builtin_amdgcn_exp2f(sc[0][c][r] * C1 - C2);
                    float p1 = __builtin_amdgcn_exp2f(sc[1][c][r] * C1 - C2);
                    if (diag) {
                        int kg = j0 + c * 16 + l16;
                        int qg = q0 + w * 16 + quad * 4 + r;
                        if (kg > qg) { p0 = 0.f; p1 = 0.f; }
                    }
                    lsum[0][r] += p0;
                    lsum[1][r] += p1;
                    Ps[w * 2304 + (quad * 4 + r) * 72 + c * 16 + l16] = f2bf(p0);
                    Ps[w * 2304 + (16 + quad * 4 + r) * 72 + c * 16 + l16] = f2bf(p1);
                }

            // O += P V; each vf feeds 2 MFMAs
#pragma unroll
            for (int ks = 0; ks < 2; ks++) {
                bf16x8 pf0 = ld_frag(&Ps[w * 2304 + l16 * 72 + ks * 32 + quad * 8]);
                bf16x8 pf1 = ld_frag(&Ps[w * 2304 + (16 + l16) * 72 + ks * 32 + quad * 8]);
#pragma unroll
                for (int od = 0; od < 8; od++) {
                    bf16x8 vf = ld_frag(&Vb[ks * 4096 + (od * 16 + l16) * 32 + (quad ^ sw) * 8]);
                    o[0][od] = __builtin_amdgcn_mfma_f32_16x16x32_bf16(pf0, vf, o[0][od], 0, 0, 0);
                    o[1][od] = __builtin_amdgcn_mfma_f32_16x16x32_bf16(pf1, vf, o[1][od], 0, 0, 0);
                }
            }
        }

        // epilogue for this q-tile
        float rl[2][4];
#pragma unroll
        for (int h = 0; h < 2; h++)
#pragma unroll
            for (int r = 0; r < 4; r++) {
                float s = lsum[h][r];
#pragma unroll
                for (int off = 1; off < 16; off <<= 1) s += __shfl_xor(s, off);
                rl[h][r] = 1.0f / s;
            }
#pragma unroll
        for (int h = 0; h < 2; h++) {
            const size_t obase = ((size_t)(b * 2048 + q0 + w * 16 + quad * 4)) * 2048 + (h0 + h) * 128;
#pragma unroll
            for (int od = 0; od < 8; od++)
#pragma unroll
                for (int r = 0; r < 4; r++)
                    attn[obase + (size_t)r * 2048 + od * 16 + l16] = f2bf(o[h][od][r] * rl[h][r]);
        }
    }
}

// ---------------------------------------------------------------- launch
extern "C" void kernel_launch(void* const* d_in, const int* in_sizes, int n_in,
                              void* d_out, int out_size, void* d_ws, size_t ws_size,
                              hipStream_t stream) {
    (void)in_sizes; (void)n_in; (void)out_size; (void)ws_size;
    const float* hidden = (const float*)d_in[0];
    const float* cosb   = (const float*)d_in[1];
    const float* sinb   = (const float*)d_in[2];
    // d_in[3] = attention_mask: causal, computed inline
    const float* q_w    = (const float*)d_in[4];
    const float* k_w    = (const float*)d_in[5];
    const float* v_w    = (const float*)d_in[6];
    const float* o_w    = (const float*)d_in[7];

    char* ws = (char*)d_ws;                                  // 104 MB used
    ushort_t* hb   = (ushort_t*)(ws);                        // [4096][2048] bf16 hidden
    ushort_t* wqkv = (ushort_t*)(ws + (16ull << 20));        // [4096][2048] bf16 q|k|v weights
    ushort_t* owb  = (ushort_t*)(ws + (32ull << 20));        // [2048][2048] bf16 o_w
    ushort_t* qkv  = (ushort_t*)(ws + (40ull << 20));        // [4096][4096] bf16 qkv proj
    ushort_t* attn = qkv;                                    // alias: qkv consumed before flash
    ushort_t* qb   = (ushort_t*)(ws + (72ull << 20));        // [2][16][2048][128]
    ushort_t* kb   = (ushort_t*)(ws + (88ull << 20));        // [2][8][2048][128]
    ushort_t* vt   = (ushort_t*)(ws + (96ull << 20));        // [2][8][128][2048]

    convert_bf16<<<8192, 256, 0, stream>>>((const f32x4*)hidden, (us4*)hb, 2097152);
    convert_bf16<<<4096, 256, 0, stream>>>((const f32x4*)q_w, (us4*)wqkv, 1048576);
    convert_bf16<<<2048, 256, 0, stream>>>((const f32x4*)k_w, (us4*)(wqkv + 2048 * 2048), 524288);
    convert_bf16<<<2048, 256, 0, stream>>>((const f32x4*)v_w, (us4*)(wqkv + 3072 * 2048), 524288);
    convert_bf16<<<4096, 256, 0, stream>>>((const f32x4*)o_w, (us4*)owb, 1048576);

    gemm_bt<ushort_t><<<dim3(32, 32), 256, 0, stream>>>(hb, wqkv, qkv, 4096, 4096, 2048);
    rope_norm<<<dim3(4096, 6), 256, 0, stream>>>(qkv, cosb, sinb, qb, kb);
    v_transpose<<<dim3(32, 2, 16), 256, 0, stream>>>(qkv, vt);
    flash_attn<<<dim3(16, 8, 2), 256, 0, stream>>>(qb, kb, vt, attn);
    gemm_bt<float><<<dim3(32, 16), 256, 0, stream>>>(attn, owb, (float*)d_out, 4096, 2048, 2048);
}

// Round 5
// 371.863 us; speedup vs baseline: 1.3360x; 1.0227x over previous
//
#include <hip/hip_runtime.h>

typedef unsigned short ushort_t;
typedef __bf16 bf16x8 __attribute__((ext_vector_type(8)));
typedef float f32x4 __attribute__((ext_vector_type(4)));
typedef unsigned int u32x4 __attribute__((ext_vector_type(4)));
typedef unsigned short us4 __attribute__((ext_vector_type(4)));
typedef unsigned short us8 __attribute__((ext_vector_type(8)));

#define DEVINL __device__ __forceinline__

DEVINL ushort_t f2bf(float f) {
    unsigned u = __float_as_uint(f);
    u += 0x7FFF + ((u >> 16) & 1);   // RNE
    return (ushort_t)(u >> 16);
}
DEVINL float bf2f(ushort_t h) { return __uint_as_float(((unsigned)h) << 16); }

DEVINL void gload_lds16(const void* g, void* l) {
    __builtin_amdgcn_global_load_lds(
        (const __attribute__((address_space(1))) void*)g,
        (__attribute__((address_space(3))) void*)l, 16, 0, 0);
}

DEVINL bf16x8 ld_frag(const ushort_t* p) {
    us8 v = *(const us8*)p;
    return __builtin_bit_cast(bf16x8, v);
}

// ---------------------------------------------------------------- fused convert
// All five f32->bf16 conversions in one launch. Segment boundaries in f32x4 units.
__global__ __launch_bounds__(256) void convert_all(const f32x4* __restrict__ h,
                                                   const f32x4* __restrict__ qw,
                                                   const f32x4* __restrict__ kw,
                                                   const f32x4* __restrict__ vw,
                                                   const f32x4* __restrict__ ow,
                                                   us4* __restrict__ hb,
                                                   us4* __restrict__ wqkv,
                                                   us4* __restrict__ owb) {
    const int N0 = 2097152;              // hidden  (2*2048*2048 /4)
    const int N1 = 1048576;              // q_w     (2048*2048 /4)
    const int N2 = 524288;               // k_w
    const int N3 = 524288;               // v_w
    int i = blockIdx.x * 256 + threadIdx.x;
    const f32x4* src; us4* dst;
    if (i < N0)                               { src = h  + i;                 dst = hb + i; }
    else if ((i -= N0) < N1)                  { src = qw + i;                 dst = wqkv + i; }
    else if ((i -= N1) < N2)                  { src = kw + i;                 dst = wqkv + 1048576 + i; }
    else if ((i -= N2) < N3)                  { src = vw + i;                 dst = wqkv + 1572864 + i; }
    else                                      { i -= N3; src = ow + i;       dst = owb + i; }
    f32x4 f = *src;
    us4 o;
    o[0] = f2bf(f[0]); o[1] = f2bf(f[1]); o[2] = f2bf(f[2]); o[3] = f2bf(f[3]);
    *dst = o;
}

// ---------------------------------------------------------------- GEMM C = A @ W^T
// A[M][K] bf16 row-major, W[N][K] bf16 row-major, C[M][N] (bf16 or f32).
// REQUIRES M == 4096 (nbx = 32) and N % 512 == 0. 1D grid of (M/128)*(N/128).
// XCD supertile swizzle: assuming round-robin block->XCD (xcd = lid%8), each
// XCD owns supertile column sx = xcd (4 A-panels = 2 MB pinned in its L2) and
// walks supertiles downward; each W-panel's 4 reader blocks are consecutive
// on the same XCD (short-window L2 reuse). Goal: stage loads hit L2 (~200cyc)
// instead of HBM (~900cyc) so the dbuf prefetch is covered by the 230cyc
// compute phase.
template <typename OutT>
__global__ __launch_bounds__(256) void gemm_bt(const ushort_t* __restrict__ A,
                                               const ushort_t* __restrict__ W,
                                               OutT* __restrict__ C,
                                               int M, int N, int K) {
    __shared__ ushort_t As[2][128 * 32];
    __shared__ ushort_t Bs[2][128 * 32];
    const int t = threadIdx.x;
    const int w = t >> 6, lane = t & 63;
    const int quad = lane >> 4, l16 = lane & 15;
    const int sw = (l16 >> 1) & 3;               // fragment-read chunk swizzle
    const int lid = blockIdx.x;
    const int xcd = lid & 7, j = lid >> 3;
    const int r = j & 15, st = j >> 4;           // r: 4x4 within supertile
    const int bm = (xcd * 4 + (r & 3)) * 128;    // A-panel column pinned per XCD
    const int bn = (st * 4 + (r >> 2)) * 128;
    const int wr = (w >> 1) * 64, wc = (w & 1) * 64;

    f32x4 acc[4][4];
#pragma unroll
    for (int i = 0; i < 4; i++)
#pragma unroll
        for (int jj = 0; jj < 4; jj++) acc[i][jj] = f32x4{0.f, 0.f, 0.f, 0.f};

    auto stage = [&](int k0, int buf) {
#pragma unroll
        for (int i = 0; i < 2; i++) {
            int u = i * 256 + t;                 // 16B-chunk; LDS dest = u*16
            int row = u >> 2;
            int ce = ((u & 3) ^ ((row >> 1) & 3)) * 8;   // swizzled source chunk
            gload_lds16(A + (size_t)(bm + row) * K + k0 + ce, (char*)As[buf] + u * 16);
            gload_lds16(W + (size_t)(bn + row) * K + k0 + ce, (char*)Bs[buf] + u * 16);
        }
    };

    stage(0, 0);
    int sbuf = 0;
    for (int k0 = 0; k0 < K; k0 += 32) {
        __syncthreads();
        const int nb = sbuf ^ 1;
        if (k0 + 32 < K) stage(k0 + 32, nb);
        const ushort_t* Ab = As[sbuf];
        const ushort_t* Bb = Bs[sbuf];
        sbuf = nb;
        bf16x8 af[4], bf[4];
#pragma unroll
        for (int mt = 0; mt < 4; mt++)
            af[mt] = ld_frag(&Ab[(wr + mt * 16 + l16) * 32 + (quad ^ sw) * 8]);
#pragma unroll
        for (int nt = 0; nt < 4; nt++)
            bf[nt] = ld_frag(&Bb[(wc + nt * 16 + l16) * 32 + (quad ^ sw) * 8]);
#pragma unroll
        for (int mt = 0; mt < 4; mt++)
#pragma unroll
            for (int nt = 0; nt < 4; nt++)
                acc[mt][nt] = __builtin_amdgcn_mfma_f32_16x16x32_bf16(af[mt], bf[nt],
                                                                      acc[mt][nt], 0, 0, 0);
    }

#pragma unroll
    for (int mt = 0; mt < 4; mt++)
#pragma unroll
        for (int nt = 0; nt < 4; nt++) {
            int row = bm + wr + mt * 16 + quad * 4;
            int col = bn + wc + nt * 16 + l16;
#pragma unroll
            for (int rr = 0; rr < 4; rr++) {
                float v = acc[mt][nt][rr];
                if constexpr (sizeof(OutT) == 2)
                    C[(size_t)(row + rr) * N + col] = (OutT)f2bf(v);
                else
                    C[(size_t)(row + rr) * N + col] = v;
            }
        }
}

// ---------------------------------------------------------------- RoPE + l2norm
__global__ __launch_bounds__(256) void rope_norm(const ushort_t* __restrict__ qkv,
                                                 const float* __restrict__ cosb,
                                                 const float* __restrict__ sinb,
                                                 ushort_t* __restrict__ q,
                                                 ushort_t* __restrict__ k) {
    int row = blockIdx.x;                 // b*2048 + s
    int b = row >> 11, s = row & 2047;
    int w = threadIdx.x >> 6, lane = threadIdx.x & 63;
    int hh = blockIdx.y * 4 + w;          // 0..23
    const ushort_t* src = qkv + (size_t)row * 4096 + hh * 128;
    float x1 = bf2f(src[lane]);
    float x2 = bf2f(src[lane + 64]);
    float c = cosb[(size_t)row * 128 + lane];
    float sn = sinb[(size_t)row * 128 + lane];
    float y1 = x1 * c + x2 * sn;
    float y2 = x2 * c - x1 * sn;
    float ss = y1 * y1 + y2 * y2;
#pragma unroll
    for (int off = 1; off < 64; off <<= 1) ss += __shfl_xor(ss, off);
    float rinv = rsqrtf(ss * (1.0f / 128.0f) + 1e-6f);
    y1 *= rinv; y2 *= rinv;
    ushort_t* dst;
    if (hh < 16) dst = q + (((size_t)(b * 16 + hh)) * 2048 + s) * 128;
    else         dst = k + (((size_t)(b * 8 + hh - 16)) * 2048 + s) * 128;
    dst[lane] = f2bf(y1);
    dst[lane + 64] = f2bf(y2);
}

// ---------------------------------------------------------------- V transpose
__global__ __launch_bounds__(256) void v_transpose(const ushort_t* __restrict__ qkv,
                                                   ushort_t* __restrict__ vt) {
    __shared__ ushort_t tile[64 * 72];
    int t = threadIdx.x;
    int s0 = blockIdx.x * 64, d0 = blockIdx.y * 64, bh = blockIdx.z;
    int b = bh >> 3, kvh = bh & 7;
    {
        int sl = t >> 2, c = t & 3;
        const ushort_t* src = qkv + (size_t)(b * 2048 + s0 + sl) * 4096 + 3072 + kvh * 128 + d0 + c * 16;
        u32x4 v0 = *(const u32x4*)src;
        u32x4 v1 = *(const u32x4*)(src + 8);
        *(u32x4*)&tile[sl * 72 + c * 16] = v0;
        *(u32x4*)&tile[sl * 72 + c * 16 + 8] = v1;
    }
    __syncthreads();
    {
        int dl = t >> 2, c = t & 3;
        alignas(16) ushort_t tmp[16];
#pragma unroll
        for (int i = 0; i < 16; i++) tmp[i] = tile[(c * 16 + i) * 72 + dl];
        ushort_t* dst = vt + (size_t)(bh * 128 + d0 + dl) * 2048 + s0 + c * 16;
        *(u32x4*)dst = *(const u32x4*)&tmp[0];
        *(u32x4*)(dst + 8) = *(const u32x4*)&tmp[8];
    }
}

// ---------------------------------------------------------------- Flash attention
// (GQA-merged, fixed-max, paired q-tiles, dbuf async staging, bank-swizzled,
//  XCD swizzle: 2 (b,kvh) groups per XCD so K/V tiles are L2-hot across the
//  16 blocks that share them). 1D grid of 256 blocks.
__global__ __launch_bounds__(256) void flash_attn(const ushort_t* __restrict__ q,
                                                  const ushort_t* __restrict__ k,
                                                  const ushort_t* __restrict__ vt,
                                                  ushort_t* __restrict__ attn) {
    __shared__ ushort_t Ks[2][4 * 64 * 32];      // 2 x 16 KB  [qd][64][32]
    __shared__ ushort_t Vts[2][2 * 128 * 32];    // 2 x 16 KB  [ks][128][32]
    __shared__ ushort_t Ps[4 * 32 * 72];         // 18 KB per-wave [head*16+row][72]
    const int t = threadIdx.x;
    const int w = t >> 6, lane = t & 63;
    const int quad = lane >> 4, l16 = lane & 15;
    const int sw = (l16 >> 1) & 3;
    const int lid = blockIdx.x;
    const int xcd = lid & 7, jj = lid >> 3;
    const int g = xcd * 2 + (jj >> 4);           // (b,kvh) group, 2 per XCD
    const int p = jj & 15;                       // q-tile pair index 0..15
    const int b = g >> 3, kvh = g & 7;
    const int h0 = kvh * 2;
    const size_t kbase = ((size_t)(b * 8 + kvh)) * 2048 * 128;
    const size_t vbase = ((size_t)(b * 8 + kvh)) * 128 * 2048;

    const float C1 = 0.12751744f;   // (1/sqrt(128)) * log2(e)
    const float C2 = 1.45f;         // fixed max in log2 domain

    auto stage = [&](int j0, int buf) {
#pragma unroll
        for (int i = 0; i < 4; i++) {            // K tile (16KB), k-blocked
            int u = i * 256 + t;
            int qd = u >> 8, rr = (u >> 2) & 63;
            int c4 = ((u & 3) ^ ((rr >> 1) & 3)) * 8;
            gload_lds16(k + kbase + (size_t)(j0 + rr) * 128 + qd * 32 + c4,
                        (char*)Ks[buf] + u * 16);
        }
#pragma unroll
        for (int i = 0; i < 4; i++) {            // Vt tile (16KB), k-blocked
            int u = i * 256 + t;
            int ks = u >> 9, dd = (u >> 2) & 127;
            int c4 = ((u & 3) ^ ((dd >> 1) & 3)) * 8;
            gload_lds16(vt + vbase + (size_t)dd * 2048 + j0 + ks * 32 + c4,
                        (char*)Vts[buf] + u * 16);
        }
    };

    const int qtile0 = 31 - p;                   // heavy pass first
    stage(0, 0);
    int sbuf = 0;

    for (int pass = 0; pass < 2; ++pass) {
        const int qi = pass ? p : qtile0;
        const int q0 = qi * 64;

        bf16x8 qf[2][4];
#pragma unroll
        for (int h = 0; h < 2; h++) {
            const size_t qbase = ((size_t)(b * 16 + h0 + h) * 2048 + q0 + w * 16 + l16) * 128;
#pragma unroll
            for (int qd = 0; qd < 4; qd++) {
                us8 v = *(const us8*)(q + qbase + qd * 32 + quad * 8);
                qf[h][qd] = __builtin_bit_cast(bf16x8, v);
            }
        }

        f32x4 o[2][8];
#pragma unroll
        for (int h = 0; h < 2; h++)
#pragma unroll
            for (int i = 0; i < 8; i++) o[h][i] = f32x4{0.f, 0.f, 0.f, 0.f};
        float lsum[2][4];
#pragma unroll
        for (int h = 0; h < 2; h++)
#pragma unroll
            for (int r = 0; r < 4; r++) lsum[h][r] = 0.f;

        for (int jt = 0; jt <= qi; ++jt) {
            const int j0 = jt * 64;
            const bool diag = (jt == qi);
            __syncthreads();                     // drains this wave's prefetch DMA
            const int nb = sbuf ^ 1;
            if (jt < qi)            stage((jt + 1) * 64, nb);
            else if (pass == 0)     stage(0, nb);
            const ushort_t* Kb = Ks[sbuf];
            const ushort_t* Vb = Vts[sbuf];
            sbuf = nb;

            // S = Q K^T for both heads; each kf feeds 2 MFMAs
            f32x4 sc[2][4];
#pragma unroll
            for (int h = 0; h < 2; h++)
#pragma unroll
                for (int c = 0; c < 4; c++) sc[h][c] = f32x4{0.f, 0.f, 0.f, 0.f};
#pragma unroll
            for (int c = 0; c < 4; c++)
#pragma unroll
                for (int qd = 0; qd < 4; qd++) {
                    bf16x8 kf = ld_frag(&Kb[qd * 2048 + (c * 16 + l16) * 32 + (quad ^ sw) * 8]);
                    sc[0][c] = __builtin_amdgcn_mfma_f32_16x16x32_bf16(qf[0][qd], kf, sc[0][c], 0, 0, 0);
                    sc[1][c] = __builtin_amdgcn_mfma_f32_16x16x32_bf16(qf[1][qd], kf, sc[1][c], 0, 0, 0);
                }

            // p = exp2(s*C1 - C2); mask only on the diagonal tile
#pragma unroll
            for (int c = 0; c < 4; c++)
#pragma unroll
                for (int r = 0; r < 4; r++) {
                    float p0 = __builtin_amdgcn_exp2f(sc[0][c][r] * C1 - C2);
                    float p1 = __builtin_amdgcn_exp2f(sc[1][c][r] * C1 - C2);
                    if (diag) {
                        int kg = j0 + c * 16 + l16;
                        int qg = q0 + w * 16 + quad * 4 + r;
                        if (kg > qg) { p0 = 0.f; p1 = 0.f; }
                    }
                    lsum[0][r] += p0;
                    lsum[1][r] += p1;
                    Ps[w * 2304 + (quad * 4 + r) * 72 + c * 16 + l16] = f2bf(p0);
                    Ps[w * 2304 + (16 + quad * 4 + r) * 72 + c * 16 + l16] = f2bf(p1);
                }

            // O += P V; each vf feeds 2 MFMAs
#pragma unroll
            for (int ks = 0; ks < 2; ks++) {
                bf16x8 pf0 = ld_frag(&Ps[w * 2304 + l16 * 72 + ks * 32 + quad * 8]);
                bf16x8 pf1 = ld_frag(&Ps[w * 2304 + (16 + l16) * 72 + ks * 32 + quad * 8]);
#pragma unroll
                for (int od = 0; od < 8; od++) {
                    bf16x8 vf = ld_frag(&Vb[ks * 4096 + (od * 16 + l16) * 32 + (quad ^ sw) * 8]);
                    o[0][od] = __builtin_amdgcn_mfma_f32_16x16x32_bf16(pf0, vf, o[0][od], 0, 0, 0);
                    o[1][od] = __builtin_amdgcn_mfma_f32_16x16x32_bf16(pf1, vf, o[1][od], 0, 0, 0);
                }
            }
        }

        // epilogue for this q-tile
        float rl[2][4];
#pragma unroll
        for (int h = 0; h < 2; h++)
#pragma unroll
            for (int r = 0; r < 4; r++) {
                float s = lsum[h][r];
#pragma unroll
                for (int off = 1; off < 16; off <<= 1) s += __shfl_xor(s, off);
                rl[h][r] = 1.0f / s;
            }
#pragma unroll
        for (int h = 0; h < 2; h++) {
            const size_t obase = ((size_t)(b * 2048 + q0 + w * 16 + quad * 4)) * 2048 + (h0 + h) * 128;
#pragma unroll
            for (int od = 0; od < 8; od++)
#pragma unroll
                for (int r = 0; r < 4; r++)
                    attn[obase + (size_t)r * 2048 + od * 16 + l16] = f2bf(o[h][od][r] * rl[h][r]);
        }
    }
}

// ---------------------------------------------------------------- launch
extern "C" void kernel_launch(void* const* d_in, const int* in_sizes, int n_in,
                              void* d_out, int out_size, void* d_ws, size_t ws_size,
                              hipStream_t stream) {
    (void)in_sizes; (void)n_in; (void)out_size; (void)ws_size;
    const float* hidden = (const float*)d_in[0];
    const float* cosb   = (const float*)d_in[1];
    const float* sinb   = (const float*)d_in[2];
    // d_in[3] = attention_mask: causal, computed inline
    const float* q_w    = (const float*)d_in[4];
    const float* k_w    = (const float*)d_in[5];
    const float* v_w    = (const float*)d_in[6];
    const float* o_w    = (const float*)d_in[7];

    char* ws = (char*)d_ws;                                  // 104 MB used
    ushort_t* hb   = (ushort_t*)(ws);                        // [4096][2048] bf16 hidden
    ushort_t* wqkv = (ushort_t*)(ws + (16ull << 20));        // [4096][2048] bf16 q|k|v weights
    ushort_t* owb  = (ushort_t*)(ws + (32ull << 20));        // [2048][2048] bf16 o_w
    ushort_t* qkv  = (ushort_t*)(ws + (40ull << 20));        // [4096][4096] bf16 qkv proj
    ushort_t* attn = qkv;                                    // alias: qkv consumed before flash
    ushort_t* qb   = (ushort_t*)(ws + (72ull << 20));        // [2][16][2048][128]
    ushort_t* kb   = (ushort_t*)(ws + (88ull << 20));        // [2][8][2048][128]
    ushort_t* vt   = (ushort_t*)(ws + (96ull << 20));        // [2][8][128][2048]

    convert_all<<<20480, 256, 0, stream>>>((const f32x4*)hidden, (const f32x4*)q_w,
                                           (const f32x4*)k_w, (const f32x4*)v_w,
                                           (const f32x4*)o_w,
                                           (us4*)hb, (us4*)wqkv, (us4*)owb);

    gemm_bt<ushort_t><<<1024, 256, 0, stream>>>(hb, wqkv, qkv, 4096, 4096, 2048);
    rope_norm<<<dim3(4096, 6), 256, 0, stream>>>(qkv, cosb, sinb, qb, kb);
    v_transpose<<<dim3(32, 2, 16), 256, 0, stream>>>(qkv, vt);
    flash_attn<<<256, 256, 0, stream>>>(qb, kb, vt, attn);
    gemm_bt<float><<<512, 256, 0, stream>>>(attn, owb, (float*)d_out, 4096, 2048, 2048);
}

// Round 6
// 370.497 us; speedup vs baseline: 1.3409x; 1.0037x over previous
//
#include <hip/hip_runtime.h>

typedef unsigned short ushort_t;
typedef __bf16 bf16x8 __attribute__((ext_vector_type(8)));
typedef float f32x4 __attribute__((ext_vector_type(4)));
typedef unsigned int u32x4 __attribute__((ext_vector_type(4)));
typedef unsigned short us4 __attribute__((ext_vector_type(4)));
typedef unsigned short us8 __attribute__((ext_vector_type(8)));

#define DEVINL __device__ __forceinline__

DEVINL ushort_t f2bf(float f) {
    unsigned u = __float_as_uint(f);
    u += 0x7FFF + ((u >> 16) & 1);   // RNE
    return (ushort_t)(u >> 16);
}
DEVINL float bf2f(ushort_t h) { return __uint_as_float(((unsigned)h) << 16); }

DEVINL void gload_lds16(const void* g, void* l) {
    __builtin_amdgcn_global_load_lds(
        (const __attribute__((address_space(1))) void*)g,
        (__attribute__((address_space(3))) void*)l, 16, 0, 0);
}

DEVINL bf16x8 ld_frag(const ushort_t* p) {
    us8 v = *(const us8*)p;
    return __builtin_bit_cast(bf16x8, v);
}

// Raw barrier with fine-grained vmcnt: keep the newest `keep` vector-memory
// ops (the distance-2 prefetch) in flight across the barrier. __syncthreads
// would emit vmcnt(0) and drain the just-issued prefetch every iteration.
#define BARRIER_KEEP4()  asm volatile("s_waitcnt vmcnt(4)\n\ts_barrier" ::: "memory")
#define BARRIER_KEEP8()  asm volatile("s_waitcnt vmcnt(8)\n\ts_barrier" ::: "memory")
#define BARRIER_KEEP0()  asm volatile("s_waitcnt vmcnt(0)\n\ts_barrier" ::: "memory")

// ---------------------------------------------------------------- fused convert
__global__ __launch_bounds__(256) void convert_all(const f32x4* __restrict__ h,
                                                   const f32x4* __restrict__ qw,
                                                   const f32x4* __restrict__ kw,
                                                   const f32x4* __restrict__ vw,
                                                   const f32x4* __restrict__ ow,
                                                   us4* __restrict__ hb,
                                                   us4* __restrict__ wqkv,
                                                   us4* __restrict__ owb) {
    const int N0 = 2097152;              // hidden  (2*2048*2048 /4)
    const int N1 = 1048576;              // q_w     (2048*2048 /4)
    const int N2 = 524288;               // k_w
    const int N3 = 524288;               // v_w
    int i = blockIdx.x * 256 + threadIdx.x;
    const f32x4* src; us4* dst;
    if (i < N0)                               { src = h  + i;                 dst = hb + i; }
    else if ((i -= N0) < N1)                  { src = qw + i;                 dst = wqkv + i; }
    else if ((i -= N1) < N2)                  { src = kw + i;                 dst = wqkv + 1048576 + i; }
    else if ((i -= N2) < N3)                  { src = vw + i;                 dst = wqkv + 1572864 + i; }
    else                                      { i -= N3; src = ow + i;       dst = owb + i; }
    f32x4 f = *src;
    us4 o;
    o[0] = f2bf(f[0]); o[1] = f2bf(f[1]); o[2] = f2bf(f[2]); o[3] = f2bf(f[3]);
    *dst = o;
}

// ---------------------------------------------------------------- GEMM C = A @ W^T
// A[M][K] bf16 row-major, W[N][K] bf16 row-major, C[M][N] (bf16 or f32).
// REQUIRES M == 4096 and N % 512 == 0, K % 32 == 0, K >= 64.
// Triple-buffered distance-2 async pipeline: at iter n, tile n is computed,
// tile n+1 is in flight (issued at n-1), tile n+2 is issued now. The barrier
// uses s_waitcnt vmcnt(4): drains tile n's 4 loads, keeps tile n+1's 4 in
// flight -> each stage has ~2 iterations (>900 cyc) of latency budget.
template <typename OutT>
__global__ __launch_bounds__(256) void gemm_bt(const ushort_t* __restrict__ A,
                                               const ushort_t* __restrict__ W,
                                               OutT* __restrict__ C,
                                               int M, int N, int K) {
    __shared__ ushort_t As[3][128 * 32];
    __shared__ ushort_t Bs[3][128 * 32];
    const int t = threadIdx.x;
    const int w = t >> 6, lane = t & 63;
    const int quad = lane >> 4, l16 = lane & 15;
    const int sw = (l16 >> 1) & 3;               // fragment-read chunk swizzle
    const int lid = blockIdx.x;
    const int xcd = lid & 7, j = lid >> 3;
    const int r = j & 15, st = j >> 4;           // 4x4 supertile walk
    const int bm = (xcd * 4 + (r & 3)) * 128;
    const int bn = (st * 4 + (r >> 2)) * 128;
    const int wr = (w >> 1) * 64, wc = (w & 1) * 64;

    f32x4 acc[4][4];
#pragma unroll
    for (int i = 0; i < 4; i++)
#pragma unroll
        for (int jj = 0; jj < 4; jj++) acc[i][jj] = f32x4{0.f, 0.f, 0.f, 0.f};

    auto stage = [&](int k0, int buf) {
#pragma unroll
        for (int i = 0; i < 2; i++) {
            int u = i * 256 + t;                 // 16B-chunk; LDS dest = u*16
            int row = u >> 2;
            int ce = ((u & 3) ^ ((row >> 1) & 3)) * 8;   // swizzled source chunk
            gload_lds16(A + (size_t)(bm + row) * K + k0 + ce, (char*)As[buf] + u * 16);
            gload_lds16(W + (size_t)(bn + row) * K + k0 + ce, (char*)Bs[buf] + u * 16);
        }
    };

    const int NIT = K >> 5;
    stage(0, 0);
    stage(32, 1);
    int cb = 0, pb = 2;                          // compute buf, prefetch buf
    for (int n = 0; n < NIT; ++n) {
        if (n + 1 < NIT) BARRIER_KEEP4();        // drain tile n, keep n+1 in flight
        else             BARRIER_KEEP0();
        if (n + 2 < NIT) stage((n + 2) * 32, pb);
        const ushort_t* Ab = As[cb];
        const ushort_t* Bb = Bs[cb];
        cb = cb == 2 ? 0 : cb + 1;
        pb = pb == 2 ? 0 : pb + 1;
        bf16x8 af[4], bf[4];
#pragma unroll
        for (int mt = 0; mt < 4; mt++)
            af[mt] = ld_frag(&Ab[(wr + mt * 16 + l16) * 32 + (quad ^ sw) * 8]);
#pragma unroll
        for (int nt = 0; nt < 4; nt++)
            bf[nt] = ld_frag(&Bb[(wc + nt * 16 + l16) * 32 + (quad ^ sw) * 8]);
#pragma unroll
        for (int mt = 0; mt < 4; mt++)
#pragma unroll
            for (int nt = 0; nt < 4; nt++)
                acc[mt][nt] = __builtin_amdgcn_mfma_f32_16x16x32_bf16(af[mt], bf[nt],
                                                                      acc[mt][nt], 0, 0, 0);
    }

#pragma unroll
    for (int mt = 0; mt < 4; mt++)
#pragma unroll
        for (int nt = 0; nt < 4; nt++) {
            int row = bm + wr + mt * 16 + quad * 4;
            int col = bn + wc + nt * 16 + l16;
#pragma unroll
            for (int rr = 0; rr < 4; rr++) {
                float v = acc[mt][nt][rr];
                if constexpr (sizeof(OutT) == 2)
                    C[(size_t)(row + rr) * N + col] = (OutT)f2bf(v);
                else
                    C[(size_t)(row + rr) * N + col] = v;
            }
        }
}

// ---------------------------------------------------------------- RoPE + l2norm
__global__ __launch_bounds__(256) void rope_norm(const ushort_t* __restrict__ qkv,
                                                 const float* __restrict__ cosb,
                                                 const float* __restrict__ sinb,
                                                 ushort_t* __restrict__ q,
                                                 ushort_t* __restrict__ k) {
    int row = blockIdx.x;                 // b*2048 + s
    int b = row >> 11, s = row & 2047;
    int w = threadIdx.x >> 6, lane = threadIdx.x & 63;
    int hh = blockIdx.y * 4 + w;          // 0..23
    const ushort_t* src = qkv + (size_t)row * 4096 + hh * 128;
    float x1 = bf2f(src[lane]);
    float x2 = bf2f(src[lane + 64]);
    float c = cosb[(size_t)row * 128 + lane];
    float sn = sinb[(size_t)row * 128 + lane];
    float y1 = x1 * c + x2 * sn;
    float y2 = x2 * c - x1 * sn;
    float ss = y1 * y1 + y2 * y2;
#pragma unroll
    for (int off = 1; off < 64; off <<= 1) ss += __shfl_xor(ss, off);
    float rinv = rsqrtf(ss * (1.0f / 128.0f) + 1e-6f);
    y1 *= rinv; y2 *= rinv;
    ushort_t* dst;
    if (hh < 16) dst = q + (((size_t)(b * 16 + hh)) * 2048 + s) * 128;
    else         dst = k + (((size_t)(b * 8 + hh - 16)) * 2048 + s) * 128;
    dst[lane] = f2bf(y1);
    dst[lane + 64] = f2bf(y2);
}

// ---------------------------------------------------------------- V transpose
__global__ __launch_bounds__(256) void v_transpose(const ushort_t* __restrict__ qkv,
                                                   ushort_t* __restrict__ vt) {
    __shared__ ushort_t tile[64 * 72];
    int t = threadIdx.x;
    int s0 = blockIdx.x * 64, d0 = blockIdx.y * 64, bh = blockIdx.z;
    int b = bh >> 3, kvh = bh & 7;
    {
        int sl = t >> 2, c = t & 3;
        const ushort_t* src = qkv + (size_t)(b * 2048 + s0 + sl) * 4096 + 3072 + kvh * 128 + d0 + c * 16;
        u32x4 v0 = *(const u32x4*)src;
        u32x4 v1 = *(const u32x4*)(src + 8);
        *(u32x4*)&tile[sl * 72 + c * 16] = v0;
        *(u32x4*)&tile[sl * 72 + c * 16 + 8] = v1;
    }
    __syncthreads();
    {
        int dl = t >> 2, c = t & 3;
        alignas(16) ushort_t tmp[16];
#pragma unroll
        for (int i = 0; i < 16; i++) tmp[i] = tile[(c * 16 + i) * 72 + dl];
        ushort_t* dst = vt + (size_t)(bh * 128 + d0 + dl) * 2048 + s0 + c * 16;
        *(u32x4*)dst = *(const u32x4*)&tmp[0];
        *(u32x4*)(dst + 8) = *(const u32x4*)&tmp[8];
    }
}

// ---------------------------------------------------------------- Flash attention
// (GQA-merged, fixed-max, paired q-tiles, TRIPLE-buffered distance-2 async
//  staging with vmcnt(8) barriers). 1D grid of 256 blocks, 1 block/CU.
__global__ __launch_bounds__(256) void flash_attn(const ushort_t* __restrict__ q,
                                                  const ushort_t* __restrict__ k,
                                                  const ushort_t* __restrict__ vt,
                                                  ushort_t* __restrict__ attn) {
    __shared__ ushort_t Ks[3][4 * 64 * 32];      // 3 x 16 KB  [qd][64][32]
    __shared__ ushort_t Vts[3][2 * 128 * 32];    // 3 x 16 KB  [ks][128][32]
    __shared__ ushort_t Ps[4 * 32 * 72];         // 18 KB per-wave scratch
    const int t = threadIdx.x;
    const int w = t >> 6, lane = t & 63;
    const int quad = lane >> 4, l16 = lane & 15;
    const int sw = (l16 >> 1) & 3;
    const int lid = blockIdx.x;
    const int xcd = lid & 7, jj = lid >> 3;
    const int g = xcd * 2 + (jj >> 4);           // (b,kvh) group, 2 per XCD
    const int p = jj & 15;                       // q-tile pair index 0..15
    const int b = g >> 3, kvh = g & 7;
    const int h0 = kvh * 2;
    const size_t kbase = ((size_t)(b * 8 + kvh)) * 2048 * 128;
    const size_t vbase = ((size_t)(b * 8 + kvh)) * 128 * 2048;

    const float C1 = 0.12751744f;   // (1/sqrt(128)) * log2(e)
    const float C2 = 1.45f;         // fixed max in log2 domain

    auto stage = [&](int j0, int buf) {
#pragma unroll
        for (int i = 0; i < 4; i++) {            // K tile (16KB), k-blocked
            int u = i * 256 + t;
            int qd = u >> 8, rr = (u >> 2) & 63;
            int c4 = ((u & 3) ^ ((rr >> 1) & 3)) * 8;
            gload_lds16(k + kbase + (size_t)(j0 + rr) * 128 + qd * 32 + c4,
                        (char*)Ks[buf] + u * 16);
        }
#pragma unroll
        for (int i = 0; i < 4; i++) {            // Vt tile (16KB), k-blocked
            int u = i * 256 + t;
            int ks = u >> 9, dd = (u >> 2) & 127;
            int c4 = ((u & 3) ^ ((dd >> 1) & 3)) * 8;
            gload_lds16(vt + vbase + (size_t)dd * 2048 + j0 + ks * 32 + c4,
                        (char*)Vts[buf] + u * 16);
        }
    };

    const int qtile0 = 31 - p;                   // heavy pass first
    const int S_total = qtile0 + 1 + p + 1;      // tile-stream length (=33)
    auto j0_of = [&](int s) { return (s <= qtile0 ? s : s - qtile0 - 1) * 64; };

    stage(j0_of(0), 0);
    stage(j0_of(1), 1);
    int sidx = 0, cb = 0, pb = 2;

    for (int pass = 0; pass < 2; ++pass) {
        const int qi = pass ? p : qtile0;
        const int q0 = qi * 64;

        bf16x8 qf[2][4];
#pragma unroll
        for (int h = 0; h < 2; h++) {
            const size_t qbase = ((size_t)(b * 16 + h0 + h) * 2048 + q0 + w * 16 + l16) * 128;
#pragma unroll
            for (int qd = 0; qd < 4; qd++) {
                us8 v = *(const us8*)(q + qbase + qd * 32 + quad * 8);
                qf[h][qd] = __builtin_bit_cast(bf16x8, v);
            }
        }

        f32x4 o[2][8];
#pragma unroll
        for (int h = 0; h < 2; h++)
#pragma unroll
            for (int i = 0; i < 8; i++) o[h][i] = f32x4{0.f, 0.f, 0.f, 0.f};
        float lsum[2][4];
#pragma unroll
        for (int h = 0; h < 2; h++)
#pragma unroll
            for (int r = 0; r < 4; r++) lsum[h][r] = 0.f;

        for (int jt = 0; jt <= qi; ++jt) {
            const int j0 = jt * 64;
            const bool diag = (jt == qi);
            if (sidx + 1 < S_total) BARRIER_KEEP8();   // drain tile sidx, keep sidx+1
            else                    BARRIER_KEEP0();
            if (sidx + 2 < S_total) stage(j0_of(sidx + 2), pb);
            const ushort_t* Kb = Ks[cb];
            const ushort_t* Vb = Vts[cb];
            cb = cb == 2 ? 0 : cb + 1;
            pb = pb == 2 ? 0 : pb + 1;
            sidx++;

            // S = Q K^T for both heads; each kf feeds 2 MFMAs
            f32x4 sc[2][4];
#pragma unroll
            for (int h = 0; h < 2; h++)
#pragma unroll
                for (int c = 0; c < 4; c++) sc[h][c] = f32x4{0.f, 0.f, 0.f, 0.f};
#pragma unroll
            for (int c = 0; c < 4; c++)
#pragma unroll
                for (int qd = 0; qd < 4; qd++) {
                    bf16x8 kf = ld_frag(&Kb[qd * 2048 + (c * 16 + l16) * 32 + (quad ^ sw) * 8]);
                    sc[0][c] = __builtin_amdgcn_mfma_f32_16x16x32_bf16(qf[0][qd], kf, sc[0][c], 0, 0, 0);
                    sc[1][c] = __builtin_amdgcn_mfma_f32_16x16x32_bf16(qf[1][qd], kf, sc[1][c], 0, 0, 0);
                }

            // p = exp2(s*C1 - C2); mask only on the diagonal tile
#pragma unroll
            for (int c = 0; c < 4; c++)
#pragma unroll
                for (int r = 0; r < 4; r++) {
                    float p0 = __builtin_amdgcn_exp2f(sc[0][c][r] * C1 - C2);
                    float p1 = __builtin_amdgcn_exp2f(sc[1][c][r] * C1 - C2);
                    if (diag) {
                        int kg = j0 + c * 16 + l16;
                        int qg = q0 + w * 16 + quad * 4 + r;
                        if (kg > qg) { p0 = 0.f; p1 = 0.f; }
                    }
                    lsum[0][r] += p0;
                    lsum[1][r] += p1;
                    Ps[w * 2304 + (quad * 4 + r) * 72 + c * 16 + l16] = f2bf(p0);
                    Ps[w * 2304 + (16 + quad * 4 + r) * 72 + c * 16 + l16] = f2bf(p1);
                }

            // O += P V; each vf feeds 2 MFMAs
#pragma unroll
            for (int ks = 0; ks < 2; ks++) {
                bf16x8 pf0 = ld_frag(&Ps[w * 2304 + l16 * 72 + ks * 32 + quad * 8]);
                bf16x8 pf1 = ld_frag(&Ps[w * 2304 + (16 + l16) * 72 + ks * 32 + quad * 8]);
#pragma unroll
                for (int od = 0; od < 8; od++) {
                    bf16x8 vf = ld_frag(&Vb[ks * 4096 + (od * 16 + l16) * 32 + (quad ^ sw) * 8]);
                    o[0][od] = __builtin_amdgcn_mfma_f32_16x16x32_bf16(pf0, vf, o[0][od], 0, 0, 0);
                    o[1][od] = __builtin_amdgcn_mfma_f32_16x16x32_bf16(pf1, vf, o[1][od], 0, 0, 0);
                }
            }
        }

        // epilogue for this q-tile
        float rl[2][4];
#pragma unroll
        for (int h = 0; h < 2; h++)
#pragma unroll
            for (int r = 0; r < 4; r++) {
                float s = lsum[h][r];
#pragma unroll
                for (int off = 1; off < 16; off <<= 1) s += __shfl_xor(s, off);
                rl[h][r] = 1.0f / s;
            }
#pragma unroll
        for (int h = 0; h < 2; h++) {
            const size_t obase = ((size_t)(b * 2048 + q0 + w * 16 + quad * 4)) * 2048 + (h0 + h) * 128;
#pragma unroll
            for (int od = 0; od < 8; od++)
#pragma unroll
                for (int r = 0; r < 4; r++)
                    attn[obase + (size_t)r * 2048 + od * 16 + l16] = f2bf(o[h][od][r] * rl[h][r]);
        }
    }
}

// ---------------------------------------------------------------- launch
extern "C" void kernel_launch(void* const* d_in, const int* in_sizes, int n_in,
                              void* d_out, int out_size, void* d_ws, size_t ws_size,
                              hipStream_t stream) {
    (void)in_sizes; (void)n_in; (void)out_size; (void)ws_size;
    const float* hidden = (const float*)d_in[0];
    const float* cosb   = (const float*)d_in[1];
    const float* sinb   = (const float*)d_in[2];
    // d_in[3] = attention_mask: causal, computed inline
    const float* q_w    = (const float*)d_in[4];
    const float* k_w    = (const float*)d_in[5];
    const float* v_w    = (const float*)d_in[6];
    const float* o_w    = (const float*)d_in[7];

    char* ws = (char*)d_ws;                                  // 104 MB used
    ushort_t* hb   = (ushort_t*)(ws);                        // [4096][2048] bf16 hidden
    ushort_t* wqkv = (ushort_t*)(ws + (16ull << 20));        // [4096][2048] bf16 q|k|v weights
    ushort_t* owb  = (ushort_t*)(ws + (32ull << 20));        // [2048][2048] bf16 o_w
    ushort_t* qkv  = (ushort_t*)(ws + (40ull << 20));        // [4096][4096] bf16 qkv proj
    ushort_t* attn = qkv;                                    // alias: qkv consumed before flash
    ushort_t* qb   = (ushort_t*)(ws + (72ull << 20));        // [2][16][2048][128]
    ushort_t* kb   = (ushort_t*)(ws + (88ull << 20));        // [2][8][2048][128]
    ushort_t* vt   = (ushort_t*)(ws + (96ull << 20));        // [2][8][128][2048]

    convert_all<<<20480, 256, 0, stream>>>((const f32x4*)hidden, (const f32x4*)q_w,
                                           (const f32x4*)k_w, (const f32x4*)v_w,
                                           (const f32x4*)o_w,
                                           (us4*)hb, (us4*)wqkv, (us4*)owb);

    gemm_bt<ushort_t><<<1024, 256, 0, stream>>>(hb, wqkv, qkv, 4096, 4096, 2048);
    rope_norm<<<dim3(4096, 6), 256, 0, stream>>>(qkv, cosb, sinb, qb, kb);
    v_transpose<<<dim3(32, 2, 16), 256, 0, stream>>>(qkv, vt);
    flash_attn<<<256, 256, 0, stream>>>(qb, kb, vt, attn);
    gemm_bt<float><<<512, 256, 0, stream>>>(attn, owb, (float*)d_out, 4096, 2048, 2048);
}